// Round 12
// baseline (1209.466 us; speedup 1.0000x reference)
//
#include <hip/hip_runtime.h>

// ---------------- problem constants ----------------
#define NB    256
#define TLEN  1632
#define HIDC  64
#define CBD   512
#define NTOK  1024
#define T2L   816
#define T4L   408
#define MTOK  (NB*T4L)     // 104448
#define M2TOK (NB*T2L)     // 208896
#define MOUT  (NB*TLEN)    // 417792

// d_out flat offsets (floats)
#define DO_OUT    ((size_t)0)
#define DO_RECON  ((size_t)417792)
#define DO_IDX    ((size_t)417795)
#define DO_QUANT  ((size_t)626691)
// scratch inside d_out (dead until commit/quant_out): fp16 xr and fp16 q1-residual
#define DO_XRH    ((size_t)417796)                  // 16B-aligned; MTOK*256 f32-units
#define DO_R1H    (DO_XRH + (size_t)MTOK*256)       // ends 53,895,172 < 54,104,067

typedef unsigned short u16;
typedef unsigned long long u64;
typedef __attribute__((ext_vector_type(8))) short short8;
typedef __attribute__((ext_vector_type(4))) float f32x4;
typedef __attribute__((ext_vector_type(8))) _Float16 half8;
typedef __attribute__((ext_vector_type(4))) _Float16 half4;

// ---------------- workspace layout (float units) ----------------
static constexpr size_t OFF_XR  = 0;                         // MTOK*512 f32
static constexpr size_t OFF_H1  = OFF_XR + (size_t)MTOK*512;
static constexpr size_t OFF_H2  = OFF_H1 + (size_t)NB*T2L*64;  // h2; reused as VQ pairs (MTOK*16 u64)
static constexpr size_t OFF_BE2 = OFF_H2 + (size_t)NB*T4L*64;
static constexpr size_t OFF_BD1 = OFF_BE2 + 8192;
static constexpr size_t OFF_BD2 = OFF_BD1 + 65536;
static constexpr size_t OFF_BX1 = OFF_BD2 + 8192;
static constexpr size_t OFF_BX2 = OFF_BX1 + 128;
static constexpr size_t OFF_ZB  = OFF_BX2 + 128;
static constexpr size_t OFF_C2  = OFF_ZB + 128;
static constexpr size_t OFF_SLOT= OFF_C2 + 2048;             // 1536 loss slots
static constexpr size_t OFF_IDXI= OFF_SLOT + 1536;
static constexpr size_t OFF_KEYS= OFF_IDXI + (size_t)MTOK*2;
static constexpr size_t OFF_FC  = OFF_KEYS + (size_t)MTOK*4;
static constexpr size_t OFF_FLAG= OFF_FC + 4;
static constexpr size_t OFF_CBH = OFF_FLAG + (size_t)MTOK*2; // 2048*512 u16 (fp16)
static constexpr size_t OFF_CBL = OFF_CBH + 524288;          // (unused)
static constexpr size_t OFF_P0  = OFF_CBL + 524288;
static constexpr size_t OFF_P1  = OFF_P0 + 131072;

// ---------------- helpers ----------------
__device__ inline u64 shfl_xor_u64_w16(u64 v, int m) {
    unsigned lo = (unsigned)v, hi = (unsigned)(v >> 32);
    lo = __shfl_xor(lo, m, 16);
    hi = __shfl_xor(hi, m, 16);
    return (((u64)hi) << 32) | lo;
}
__device__ inline u64 packkey(float d, int n) {
    unsigned u = __float_as_uint(d);
    u = (u & 0x80000000u) ? ~u : (u | 0x80000000u);
    return (((u64)u) << 32) | (unsigned)n;
}
__device__ inline float unpackd(u64 k) {
    unsigned u = (unsigned)(k >> 32);
    u = (u & 0x80000000u) ? (u & 0x7fffffffu) : ~u;
    return __uint_as_float(u);
}
__device__ inline void merge2(u64& k1, u64& k2, u64 o1, u64 o2) {
    u64 n1 = (k1 < o1) ? k1 : o1;
    u64 hi = (k1 < o1) ? o1 : k1;
    u64 cand = (k1 <= o1) ? k2 : o2;
    u64 n2 = (hi < cand) ? hi : cand;
    k1 = n1; k2 = n2;
}
__device__ inline half4 cvt_h4(float4 v) {
    half4 h;
    h.x = (_Float16)v.x; h.y = (_Float16)v.y;
    h.z = (_Float16)v.z; h.w = (_Float16)v.w;
    return h;
}
// async global->LDS copy, 16B per lane, dest = wave-uniform base + lane*16
__device__ inline void gll16(const u16* g, u16* l) {
    __builtin_amdgcn_global_load_lds((const __attribute__((address_space(1))) void*)g,
                                     (__attribute__((address_space(3))) void*)l, 16, 0, 0);
}

// ---------------- fused setup: weight prep + codebook fp16 + codebook norms ----------------
__global__ void setup_kernel(const float* __restrict__ We2, const float* __restrict__ Wtd1,
                             const float* __restrict__ Wtd2, const float* __restrict__ bd1,
                             const float* __restrict__ bd2, const float* __restrict__ cbs,
                             float* __restrict__ Be2, float* __restrict__ Bd1,
                             float* __restrict__ Bd2, float* __restrict__ bx1, float* __restrict__ bx2,
                             u16* __restrict__ cbh, float* __restrict__ c2) {
    size_t t = (size_t)blockIdx.x * 256 + threadIdx.x;   // grid 1024 -> 262144 threads
    {
        float4 v = *(const float4*)(cbs + t * 4);
        *(half4*)&cbh[t * 4] = cvt_h4(v);
    }
    {
        int w = (int)(t >> 6);
        int lane = threadIdx.x & 63;
        if (w < 2048) {
            const float* r = cbs + (size_t)w * 512;
            float4 a = *(const float4*)(r + lane * 8);
            float4 b = *(const float4*)(r + lane * 8 + 4);
            float s = a.x*a.x + a.y*a.y + a.z*a.z + a.w*a.w + b.x*b.x + b.y*b.y + b.z*b.z + b.w*b.w;
            #pragma unroll
            for (int o = 32; o > 0; o >>= 1) s += __shfl_down(s, o, 64);
            if (lane == 0) c2[w] = s;
        }
    }
    size_t stride = (size_t)gridDim.x * 256;
    for (size_t x = t; x < 64 * 128; x += stride) {
        int c = (int)(x >> 7), k = (int)(x & 127);
        Be2[x] = We2[c * 128 + ((k & 63) << 1) + (k >> 6)];
    }
    for (size_t x = t; x < 128 * 512; x += stride) {
        int n = (int)(x >> 9), k = (int)(x & 511);
        Bd1[x] = Wtd1[k * 128 + n];
    }
    for (size_t x = t; x < 128 * 64; x += stride) {
        int n = (int)(x >> 6), k = (int)(x & 63);
        Bd2[x] = Wtd2[k * 128 + n];
    }
    for (size_t x = t; x < 128; x += stride) { bx1[x] = bd1[x >> 1]; bx2[x] = bd2[x >> 1]; }
}

// ---------------- encoder conv1 ----------------
__global__ void enc1_kernel(const float* __restrict__ img, const float* __restrict__ W,
                            const float* __restrict__ bias, float* __restrict__ h1) {
    int idx = blockIdx.x * 256 + threadIdx.x;
    int c = idx & 63;
    int t = (idx >> 6) % T2L;
    int b = idx / (64 * T2L);
    float v = W[c * 2] * img[(size_t)b * TLEN + 2 * t] +
              W[c * 2 + 1] * img[(size_t)b * TLEN + 2 * t + 1] + bias[c];
    h1[idx] = fmaxf(v, 0.f);
}

// ---------------- generic NT SGEMM (cmode0 only); optional fp16 mirror of C ----------------
__global__ __launch_bounds__(256) void gemm_nt(const float* __restrict__ A, const float* __restrict__ Bw,
                        const float* __restrict__ bias, float* __restrict__ C,
                        int M, int N, int K, int amode, int relu, u16* __restrict__ xh) {
    __shared__ float As[32][132];
    __shared__ float Bs[32][68];
    int m0 = blockIdx.x * 128;
    int n0 = blockIdx.y * 64;
    int tid = threadIdx.x;
    int tx = tid & 15;
    int ty = tid >> 4;
    float acc[8][4];
    #pragma unroll
    for (int i = 0; i < 8; ++i)
        #pragma unroll
        for (int j = 0; j < 4; ++j) acc[i][j] = 0.f;

    for (int k0 = 0; k0 < K; k0 += 32) {
        #pragma unroll
        for (int i = 0; i < 4; ++i) {
            int idx = tid + i * 256;
            int row = idx >> 3;
            int kq = idx & 7;
            int m = m0 + row;
            size_t base;
            if (amode == 0) base = (size_t)m * K;
            else            base = (size_t)(((m / T4L) * T2L + 2 * (m % T4L)) * 64);
            float4 v = *(const float4*)(A + base + k0 + kq * 4);
            int kk = kq * 4;
            As[kk + 0][row] = v.x; As[kk + 1][row] = v.y;
            As[kk + 2][row] = v.z; As[kk + 3][row] = v.w;
        }
        #pragma unroll
        for (int i = 0; i < 2; ++i) {
            int idx = tid + i * 256;
            int row = idx >> 3;
            int kq = idx & 7;
            float4 v = *(const float4*)(Bw + (size_t)(n0 + row) * K + k0 + kq * 4);
            int kk = kq * 4;
            Bs[kk + 0][row] = v.x; Bs[kk + 1][row] = v.y;
            Bs[kk + 2][row] = v.z; Bs[kk + 3][row] = v.w;
        }
        __syncthreads();
        #pragma unroll
        for (int kk = 0; kk < 32; ++kk) {
            float a[8], bf[4];
            float4 a0 = *(const float4*)&As[kk][ty * 8];
            float4 a1 = *(const float4*)&As[kk][ty * 8 + 4];
            a[0]=a0.x; a[1]=a0.y; a[2]=a0.z; a[3]=a0.w;
            a[4]=a1.x; a[5]=a1.y; a[6]=a1.z; a[7]=a1.w;
            float4 b0 = *(const float4*)&Bs[kk][tx * 4];
            bf[0]=b0.x; bf[1]=b0.y; bf[2]=b0.z; bf[3]=b0.w;
            #pragma unroll
            for (int i = 0; i < 8; ++i)
                #pragma unroll
                for (int j = 0; j < 4; ++j) acc[i][j] += a[i] * bf[j];
        }
        __syncthreads();
    }
    #pragma unroll
    for (int i = 0; i < 8; ++i) {
        int m = m0 + ty * 8 + i;
        float4 v;
        v.x = acc[i][0] + bias[n0 + tx * 4 + 0];
        v.y = acc[i][1] + bias[n0 + tx * 4 + 1];
        v.z = acc[i][2] + bias[n0 + tx * 4 + 2];
        v.w = acc[i][3] + bias[n0 + tx * 4 + 3];
        if (relu) { v.x=fmaxf(v.x,0.f); v.y=fmaxf(v.y,0.f); v.z=fmaxf(v.z,0.f); v.w=fmaxf(v.w,0.f); }
        *(float4*)(C + (size_t)m * N + n0 + tx * 4) = v;
        if (xh) *(half4*)&xh[(size_t)m * N + n0 + tx * 4] = cvt_h4(v);
    }
}

// ---------------- q1 residual prep: r1h = xrh - cbh0[i0], packed fp16 ----------------
__global__ void r1_prep(const u16* __restrict__ xrh, const u16* __restrict__ cbh0,
                        const u64* __restrict__ keys, u16* __restrict__ r1h) {
    int m = blockIdx.x * 8 + (threadIdx.x >> 5);
    int l = threadIdx.x & 31;
    int i0 = (int)(keys[m] & 0xFFFFFFFFull);
    const half8* xp = (const half8*)(xrh + (size_t)m * 512 + l * 16);
    const half8* cp = (const half8*)(cbh0 + (size_t)i0 * 512 + l * 16);
    half8* rp = (half8*)(r1h + (size_t)m * 512 + l * 16);
    rp[0] = xp[0] - cp[0];
    rp[1] = xp[1] - cp[1];
}

// ---------------- VQ: 128x128 tile, 4 waves, quad-buffer + counted-vmcnt pipeline ----------------
// r11 pipeline (verified) at HALF tile: LDS 64KB -> 2 independent blocks/CU, so while one
// block's waves sit at vmcnt+barrier the other block's waves issue ds_read/MFMA (m114
// stall-filling -- impossible at r11's 1 block/CU where all waves shared one barrier).
// Same segment formulas (A and B tiles both 128x32/step), same vmcnt literals (4 gll/wave/
// batch -> steady 12 outstanding -> vmcnt(8), tail 4/0), same XOR swizzle, same epilogue
// (half-width). XCD swizzle: nwg = 6528 = 8*816, bijective. Distances bit-identical.
__global__ __launch_bounds__(256, 2) void vq_f16_gll(
    const u16* __restrict__ Ah, const u16* __restrict__ cbh,
    const float* __restrict__ c2, u64* __restrict__ pairs)
{
    __shared__ __align__(16) u16 As[4][128 * 32];   // 32 KB
    __shared__ __align__(16) u16 Bs[4][128 * 32];   // 32 KB
    int tid = threadIdx.x;
    // XCD-aware bijective remap: f -> wg so each XCD (f%8) owns contiguous 816 wgs
    int f = blockIdx.y * 8 + blockIdx.x;
    int wg = (f & 7) * 816 + (f >> 3);
    int n0 = (wg & 7) * 128, m0 = (wg >> 3) * 128;
    int nblk = wg & 7;
    int lane = tid & 63, wid = tid >> 6;            // 4 waves
    int lm = lane & 15, quad = lane >> 4;
    int wm = wid >> 1, wn = wid & 1;                // 2x2 wave grid; wave tile 64(M) x 64(N)

    f32x4 acc[4][4];
    #pragma unroll
    for (int i = 0; i < 4; ++i)
        #pragma unroll
        for (int j = 0; j < 4; ++j) acc[i][j] = (f32x4){0.f, 0.f, 0.f, 0.f};

    // gll mapping: 8 1KB-segments per operand; wave w stages segments {2w, 2w+1}.
    // Segment s covers rows s*16..s*16+15; lane l -> row s*16+(l>>2), chunk-slot l&3,
    // global chunk pre-swizzled: (l&3) ^ ((row>>1)&3). LDS dest wave-uniform s*512 (u16).
    int srow[2], schk[2];
    #pragma unroll
    for (int i = 0; i < 2; ++i) {
        int s = wid * 2 + i;
        srow[i] = s * 16 + (lane >> 2);
        schk[i] = (lane & 3) ^ ((srow[i] >> 1) & 3);
    }

#define VQ_GLL(BUF, K0)                                                               \
    _Pragma("unroll")                                                                 \
    for (int i = 0; i < 2; ++i) {                                                     \
        int s = wid * 2 + i;                                                          \
        gll16(Ah + (size_t)(m0 + srow[i]) * 512 + (K0) + schk[i] * 8,                 \
              &As[BUF][s * 512]);                                                     \
        gll16(cbh + (size_t)(n0 + srow[i]) * 512 + (K0) + schk[i] * 8,                \
              &Bs[BUF][s * 512]);                                                     \
    }

#define VQ_COMPUTE(BUF) {                                                             \
        half8 ah[4];                                                                  \
        _Pragma("unroll")                                                             \
        for (int mt = 0; mt < 4; ++mt) {                                              \
            int r = wm * 64 + mt * 16 + lm;                                           \
            ah[mt] = *(const half8*)&As[BUF][r * 32 + ((quad ^ ((r >> 1) & 3)) * 8)]; \
        }                                                                             \
        _Pragma("unroll")                                                             \
        for (int nt = 0; nt < 4; ++nt) {                                              \
            int rn = wn * 64 + nt * 16 + lm;                                          \
            half8 bh = *(const half8*)&Bs[BUF][rn * 32 + ((quad ^ ((rn >> 1) & 3)) * 8)]; \
            _Pragma("unroll")                                                         \
            for (int mt = 0; mt < 4; ++mt)                                            \
                acc[mt][nt] = __builtin_amdgcn_mfma_f32_16x16x32_f16(ah[mt], bh, acc[mt][nt], 0, 0, 0); \
        }                                                                             \
    }

    // prologue: batches 0,1 in flight (8 outstanding VMEM per wave)
    VQ_GLL(0, 0);
    VQ_GLL(1, 32);
    #pragma unroll
    for (int t = 0; t < 16; ++t) {
        if (t + 2 < 16) VQ_GLL((t + 2) & 3, (t + 2) * 32);   // 4 more -> 12 outstanding
        // wait until batch t's 4 ops retired (in-order retirement, m135)
        if (t <= 13)      asm volatile("s_waitcnt vmcnt(8)" ::: "memory");
        else if (t == 14) asm volatile("s_waitcnt vmcnt(4)" ::: "memory");
        else              asm volatile("s_waitcnt vmcnt(0)" ::: "memory");
        __builtin_amdgcn_s_barrier();                         // everyone's batch t landed
        __builtin_amdgcn_sched_barrier(0);                    // pin ds_reads below barrier
        VQ_COMPUTE(t & 3);
    }
#undef VQ_GLL
#undef VQ_COMPUTE

    float c2v[4];
    #pragma unroll
    for (int nt = 0; nt < 4; ++nt) c2v[nt] = c2[n0 + wn * 64 + nt * 16 + lm];

    u64* scr = (u64*)&As[0][0];   // [2 wn][128 tokens][2] = 512 u64 = 4KB (fits in As[0])
    #pragma unroll
    for (int mt = 0; mt < 4; ++mt) {
        #pragma unroll
        for (int rg = 0; rg < 4; ++rg) {
            int tl = wm * 64 + mt * 16 + quad * 4 + rg;
            u64 k1 = ~0ull, k2 = ~0ull;
            #pragma unroll
            for (int nt = 0; nt < 4; ++nt) {
                float d = c2v[nt] - 2.0f * acc[mt][nt][rg];
                u64 k = packkey(d, n0 + wn * 64 + nt * 16 + lm);
                if (k < k1) { k2 = k1; k1 = k; } else if (k < k2) { k2 = k; }
            }
            #pragma unroll
            for (int s = 1; s < 16; s <<= 1) {
                u64 o1 = shfl_xor_u64_w16(k1, s);
                u64 o2 = shfl_xor_u64_w16(k2, s);
                merge2(k1, k2, o1, o2);
            }
            if (lm == 0) { scr[wn * 256 + tl * 2] = k1; scr[wn * 256 + tl * 2 + 1] = k2; }
        }
    }
    __syncthreads();
    if (tid < 128) {
        u64 a1 = scr[tid * 2], a2 = scr[tid * 2 + 1];
        merge2(a1, a2, scr[256 + tid * 2], scr[256 + tid * 2 + 1]);
        size_t base = (size_t)(m0 + tid) * 16 + nblk * 2;
        pairs[base] = a1; pairs[base + 1] = a2;
    }
}

// ---------------- reduce: global top2 per token from 8 block-pairs ----------------
__global__ void vq_reduce(const u64* __restrict__ pairs, u64* __restrict__ keybuf,
                          int* __restrict__ fc, int* __restrict__ flaglist, float tau) {
    int m = blockIdx.x * 256 + threadIdx.x;
    const u64* p = pairs + (size_t)m * 16;
    u64 k1 = ~0ull, k2 = ~0ull;
    #pragma unroll
    for (int i = 0; i < 16; ++i) {
        u64 k = p[i];
        if (k < k1) { k2 = k1; k1 = k; } else if (k < k2) { k2 = k; }
    }
    keybuf[m] = k1;
    if (unpackd(k2) - unpackd(k1) < tau) {
        int pos = atomicAdd(fc, 1);
        flaglist[pos] = m;
    }
}

// ---------------- rescue: exact fp32 argmin for flagged tokens ----
__global__ void vq_rescue(const float* __restrict__ xr, const float* __restrict__ cb,
                          const float* __restrict__ c2, const float* __restrict__ cb0,
                          const u64* __restrict__ prevkeys,
                          const int* __restrict__ fc, const int* __restrict__ flaglist,
                          u64* __restrict__ keybuf) {
    __shared__ u64 red[4];
    int cnt = *fc;
    int lane = threadIdx.x & 63, wid = threadIdx.x >> 6;
    for (int f = blockIdx.x; f < cnt; f += gridDim.x) {
        int m = flaglist[f];
        float4 rv0 = *(const float4*)(xr + (size_t)m * 512 + lane * 8);
        float4 rv1 = *(const float4*)(xr + (size_t)m * 512 + lane * 8 + 4);
        if (cb0) {
            size_t co = (size_t)(prevkeys[m] & 0xFFFFFFFFull) * 512;
            float4 c0 = *(const float4*)(cb0 + co + lane * 8);
            float4 c1 = *(const float4*)(cb0 + co + lane * 8 + 4);
            rv0.x -= c0.x; rv0.y -= c0.y; rv0.z -= c0.z; rv0.w -= c0.w;
            rv1.x -= c1.x; rv1.y -= c1.y; rv1.z -= c1.z; rv1.w -= c1.w;
        }
        u64 best = ~0ull;
        for (int c = wid * 256; c < wid * 256 + 256; ++c) {
            const float* cp = cb + (size_t)c * 512 + lane * 8;
            float4 c0 = *(const float4*)cp;
            float4 c1 = *(const float4*)(cp + 4);
            float p = rv0.x*c0.x + rv0.y*c0.y + rv0.z*c0.z + rv0.w*c0.w
                    + rv1.x*c1.x + rv1.y*c1.y + rv1.z*c1.z + rv1.w*c1.w;
            #pragma unroll
            for (int s = 1; s < 64; s <<= 1) p += __shfl_xor(p, s, 64);
            u64 k = packkey(c2[c] - 2.0f * p, c);
            if (k < best) best = k;
        }
        if (lane == 0) red[wid] = best;
        __syncthreads();
        if (threadIdx.x == 0) {
            u64 b = red[0];
            if (red[1] < b) b = red[1];
            if (red[2] < b) b = red[2];
            if (red[3] < b) b = red[3];
            keybuf[m] = b;
        }
        __syncthreads();
    }
}

// ---------------- commit + indices (wave per token, exact fp32 losses) ----------------
__global__ void commit_idx_kernel(const float* __restrict__ xr,
                                  const float* __restrict__ cb0f, const float* __restrict__ cb1f,
                                  const u64* __restrict__ keys0, const u64* __restrict__ keys1,
                                  float* __restrict__ idx_f, int* __restrict__ idx_i,
                                  float* __restrict__ slots) {
    int tid = threadIdx.x;
    int lane = tid & 63;
    int m = blockIdx.x * 4 + (tid >> 6);
    unsigned i0 = (unsigned)(keys0[m] & 0xFFFFFFFFull);
    unsigned i1 = (unsigned)(keys1[m] & 0xFFFFFFFFull);
    const float* x = xr + (size_t)m * 512 + lane * 8;
    const float* c0 = cb0f + (size_t)i0 * 512 + lane * 8;
    const float* c1 = cb1f + (size_t)i1 * 512 + lane * 8;
    float4 x0 = *(const float4*)x, x1 = *(const float4*)(x + 4);
    float4 a0 = *(const float4*)c0, a1 = *(const float4*)(c0 + 4);
    float4 b0 = *(const float4*)c1, b1 = *(const float4*)(c1 + 4);
    x0.x -= a0.x; x0.y -= a0.y; x0.z -= a0.z; x0.w -= a0.w;
    x1.x -= a1.x; x1.y -= a1.y; x1.z -= a1.z; x1.w -= a1.w;
    float s1 = x0.x*x0.x + x0.y*x0.y + x0.z*x0.z + x0.w*x0.w
             + x1.x*x1.x + x1.y*x1.y + x1.z*x1.z + x1.w*x1.w;
    x0.x -= b0.x; x0.y -= b0.y; x0.z -= b0.z; x0.w -= b0.w;
    x1.x -= b1.x; x1.y -= b1.y; x1.z -= b1.z; x1.w -= b1.w;
    float s2 = x0.x*x0.x + x0.y*x0.y + x0.z*x0.z + x0.w*x0.w
             + x1.x*x1.x + x1.y*x1.y + x1.z*x1.z + x1.w*x1.w;
    #pragma unroll
    for (int o = 32; o > 0; o >>= 1) { s1 += __shfl_down(s1, o, 64); s2 += __shfl_down(s2, o, 64); }
    if (lane == 0) {
        atomicAdd(&slots[512 + (m & 511)], s1);
        atomicAdd(&slots[1024 + (m & 511)], s2);
        idx_f[(size_t)m * 2]     = (float)i0;
        idx_f[(size_t)m * 2 + 1] = (float)i1;
        idx_i[m * 2] = (int)i0;
        idx_i[m * 2 + 1] = (int)i1;
    }
}

// ---------------- quantized output (channel-major) via LDS transpose ----------------
__global__ void quant_out_kernel(const float* __restrict__ cb0, const float* __restrict__ cb1,
                                 const int* __restrict__ idxi, float* __restrict__ out4) {
    __shared__ float buf[64][129];
    __shared__ int i0s[64], i1s[64];
    int b = blockIdx.x;
    int t0 = blockIdx.y * 64;
    int c0 = blockIdx.z * 128;
    int tid = threadIdx.x;
    if (tid < 64) {
        int t = t0 + tid;
        int i0 = 0, i1 = 0;
        if (t < T4L) { i0 = idxi[(b * T4L + t) * 2]; i1 = idxi[(b * T4L + t) * 2 + 1]; }
        i0s[tid] = i0; i1s[tid] = i1;
    }
    __syncthreads();
    int cl = tid & 127, th = tid >> 7;
    for (int t = th; t < 64; t += 2) {
        if (t0 + t < T4L)
            buf[t][cl] = cb0[(size_t)i0s[t] * 512 + c0 + cl] + cb1[(size_t)i1s[t] * 512 + c0 + cl];
    }
    __syncthreads();
    int lane = tid & 63, ch = tid >> 6;
    for (int cc = ch; cc < 128; cc += 4) {
        int t = t0 + lane;
        if (t < T4L) out4[((size_t)b * 512 + c0 + cc) * T4L + t] = buf[lane][cc];
    }
}

// ---------------- decoder stage-1 via code tables ----------------
__global__ void d1_gather_kernel(const float* __restrict__ P0, const float* __restrict__ P1,
                                 const int* __restrict__ idxi, const float* __restrict__ bx1,
                                 float* __restrict__ d1) {
    int x = blockIdx.x * 256 + threadIdx.x;
    int n = x & 127;
    int m = x >> 7;
    int b = m / T4L, t = m % T4L;
    int i0 = idxi[m * 2], i1 = idxi[m * 2 + 1];
    float v = P0[i0 * 128 + n] + P1[i1 * 128 + n] + bx1[n];
    v = fmaxf(v, 0.f);
    d1[((size_t)(b * T2L + 2 * t + (n & 1))) * 64 + (n >> 1)] = v;
}

// ---------------- fused convT2 + final 1x1 conv + recon loss ----------------
__global__ __launch_bounds__(256) void dec2_fused(
    const float* __restrict__ d1, const float* __restrict__ Bd2, const float* __restrict__ bx2,
    const float* __restrict__ W3, const float* __restrict__ b3, const float* __restrict__ img,
    float* __restrict__ out, float* __restrict__ slots)
{
    __shared__ float As[32][132];
    __shared__ float Bs[32][132];
    __shared__ float w3s[64];
    int m0 = blockIdx.x * 128;
    int tid = threadIdx.x;
    int tx = tid & 15;
    int ty = tid >> 4;
    if (tid < 64) w3s[tid] = W3[tid];
    float acc[8][8];
    #pragma unroll
    for (int i = 0; i < 8; ++i)
        #pragma unroll
        for (int j = 0; j < 8; ++j) acc[i][j] = 0.f;

    for (int k0 = 0; k0 < 64; k0 += 32) {
        #pragma unroll
        for (int i = 0; i < 4; ++i) {
            int idx = tid + i * 256;
            int row = idx >> 3;
            int kq = idx & 7;
            float4 v = *(const float4*)(d1 + (size_t)(m0 + row) * 64 + k0 + kq * 4);
            int kk = kq * 4;
            As[kk + 0][row] = v.x; As[kk + 1][row] = v.y;
            As[kk + 2][row] = v.z; As[kk + 3][row] = v.w;
        }
        #pragma unroll
        for (int i = 0; i < 4; ++i) {
            int idx = tid + i * 256;
            int row = idx >> 3;
            int kq = idx & 7;
            float4 v = *(const float4*)(Bd2 + (size_t)row * 64 + k0 + kq * 4);
            int kk = kq * 4;
            Bs[kk + 0][row] = v.x; Bs[kk + 1][row] = v.y;
            Bs[kk + 2][row] = v.z; Bs[kk + 3][row] = v.w;
        }
        __syncthreads();
        #pragma unroll
        for (int kk = 0; kk < 32; ++kk) {
            float a[8], bf[8];
            float4 a0 = *(const float4*)&As[kk][ty * 8];
            float4 a1 = *(const float4*)&As[kk][ty * 8 + 4];
            a[0]=a0.x; a[1]=a0.y; a[2]=a0.z; a[3]=a0.w;
            a[4]=a1.x; a[5]=a1.y; a[6]=a1.z; a[7]=a1.w;
            float4 b0 = *(const float4*)&Bs[kk][tx * 4];
            float4 b1 = *(const float4*)&Bs[kk][64 + tx * 4];
            bf[0]=b0.x; bf[1]=b0.y; bf[2]=b0.z; bf[3]=b0.w;
            bf[4]=b1.x; bf[5]=b1.y; bf[6]=b1.z; bf[7]=b1.w;
            #pragma unroll
            for (int i = 0; i < 8; ++i)
                #pragma unroll
                for (int j = 0; j < 8; ++j) acc[i][j] += a[i] * bf[j];
        }
        __syncthreads();
    }
    float bb3 = b3[0];
    float local = 0.f;
    #pragma unroll
    for (int i = 0; i < 8; ++i) {
        float s0 = 0.f, s1 = 0.f;
        #pragma unroll
        for (int j = 0; j < 4; ++j) {
            int n = tx * 4 + j;
            float v = fmaxf(acc[i][j] + bx2[n], 0.f);
            float w = w3s[n >> 1];
            if (j & 1) s1 += w * v; else s0 += w * v;
            int n2 = 64 + tx * 4 + j;
            float v2 = fmaxf(acc[i][j + 4] + bx2[n2], 0.f);
            float w2 = w3s[n2 >> 1];
            if (j & 1) s1 += w2 * v2; else s0 += w2 * v2;
        }
        #pragma unroll
        for (int o = 8; o > 0; o >>= 1) { s0 += __shfl_down(s0, o, 16); s1 += __shfl_down(s1, o, 16); }
        if (tx == 0) {
            int m = m0 + ty * 8 + i;
            int b = m / T2L, t2 = m % T2L;
            size_t o0 = (size_t)b * TLEN + 2 * t2;
            float v0 = s0 + bb3, v1 = s1 + bb3;
            out[o0] = v0; out[o0 + 1] = v1;
            float e0 = img[o0] - v0, e1 = img[o0 + 1] - v1;
            local += e0 * e0 + e1 * e1;
        }
    }
    if (tx == 0) atomicAdd(&slots[(blockIdx.x * 16 + ty) & 511], local);
}

// ---------------- finalize losses ----------------
__global__ void finalize_kernel(const float* __restrict__ slots, float* __restrict__ out_scalars) {
    __shared__ float red[256];
    int tid = threadIdx.x;
    for (int which = 0; which < 3; ++which) {
        float s = slots[which * 512 + tid] + slots[which * 512 + tid + 256];
        red[tid] = s; __syncthreads();
        for (int st = 128; st > 0; st >>= 1) { if (tid < st) red[tid] += red[tid + st]; __syncthreads(); }
        if (tid == 0) {
            float denom = (which == 0) ? (float)MOUT : (float)((size_t)MTOK * 512);
            out_scalars[which] = red[0] / denom;
        }
        __syncthreads();
    }
}

// ---------------- launch ----------------
extern "C" void kernel_launch(void* const* d_in, const int* in_sizes, int n_in,
                              void* d_out, int out_size, void* d_ws, size_t ws_size,
                              hipStream_t stream) {
    const float* img  = (const float*)d_in[0];
    const float* We1  = (const float*)d_in[1];
    const float* be1  = (const float*)d_in[2];
    const float* We2  = (const float*)d_in[3];
    const float* be2  = (const float*)d_in[4];
    const float* We3  = (const float*)d_in[5];
    const float* be3  = (const float*)d_in[6];
    const float* cbs  = (const float*)d_in[7];
    const float* Wtd1 = (const float*)d_in[8];
    const float* bd1  = (const float*)d_in[9];
    const float* Wtd2 = (const float*)d_in[10];
    const float* bd2  = (const float*)d_in[11];
    const float* Wd3  = (const float*)d_in[12];
    const float* bd3  = (const float*)d_in[13];

    float* w = (float*)d_ws;
    float* xr   = w + OFF_XR;
    float* h1   = w + OFF_H1;
    float* h2   = w + OFF_H2;
    float* Be2  = w + OFF_BE2;
    float* Bd1  = w + OFF_BD1;
    float* Bd2  = w + OFF_BD2;
    float* bx1  = w + OFF_BX1;
    float* bx2  = w + OFF_BX2;
    float* zerob= w + OFF_ZB;
    float* c2   = w + OFF_C2;
    float* slots= w + OFF_SLOT;
    int*   idxi = (int*)(w + OFF_IDXI);
    u64*   keys = (u64*)(w + OFF_KEYS);
    int*   fc   = (int*)(w + OFF_FC);
    int*   flag = (int*)(w + OFF_FLAG);
    u16*   cbh  = (u16*)(w + OFF_CBH);
    float* P0   = w + OFF_P0;
    float* P1   = w + OFF_P1;
    u64*   pairs= (u64*)(w + OFF_H2);   // h2 dead after enc3; MTOK*16 u64 = 13.4MB << h2 size

    float* outp = (float*)d_out;
    float* out0   = outp + DO_OUT;
    float* oscal  = outp + DO_RECON;
    float* idxf   = outp + DO_IDX;
    float* qout   = outp + DO_QUANT;
    // d_out scratch (dead until commit/quant_out, which run after all consumers):
    u16*   xrh    = (u16*)(outp + DO_XRH);
    u16*   r1h    = (u16*)(outp + DO_R1H);

    hipMemsetAsync(slots, 0, 1536 * sizeof(float), stream);
    hipMemsetAsync(fc, 0, 2 * sizeof(int), stream);
    hipMemsetAsync(zerob, 0, 128 * sizeof(float), stream);

    setup_kernel<<<1024, 256, 0, stream>>>(We2, Wtd1, Wtd2, bd1, bd2, cbs,
                                           Be2, Bd1, Bd2, bx1, bx2, cbh, c2);

    const float* cb1p = cbs + (size_t)NTOK * CBD;

    // decoder stage-1 code tables: P = cb . Bd1^T  (P0,P1 contiguous -> single M=2048 gemm)
    gemm_nt<<<dim3(16, 2), 256, 0, stream>>>(cbs, Bd1, zerob, P0, 2048, 128, 512, 0, 0, nullptr);

    // encoder
    enc1_kernel<<<(NB * T2L * HIDC) / 256, 256, 0, stream>>>(img, We1, be1, h1);
    gemm_nt<<<dim3(MTOK / 128, 1), 256, 0, stream>>>(h1, Be2, be2, h2, MTOK, 64, 128, 1, 1, nullptr);
    gemm_nt<<<dim3(MTOK / 128, 8), 256, 0, stream>>>(h2, We3, be3, xr, MTOK, 512, 64, 0, 0, xrh);

    // residual VQ, q = 0: pipelined pure-gll fp16 MFMA, TAU 0.05
    vq_f16_gll<<<dim3(8, MTOK / 128), 256, 0, stream>>>(xrh, cbh, c2, pairs);
    vq_reduce<<<MTOK / 256, 256, 0, stream>>>(pairs, keys, fc + 0, flag, 0.05f);
    vq_rescue<<<1024, 256, 0, stream>>>(xr, cbs, c2, nullptr, nullptr, fc + 0, flag, keys);
    // q = 1: r1h = xrh - cbh0[i0] (packed fp16); TAU 0.15
    r1_prep<<<MTOK / 8, 256, 0, stream>>>(xrh, cbh, keys, r1h);
    vq_f16_gll<<<dim3(8, MTOK / 128), 256, 0, stream>>>(r1h, cbh + (size_t)NTOK * 512, c2 + NTOK, pairs);
    vq_reduce<<<MTOK / 256, 256, 0, stream>>>(pairs, keys + MTOK, fc + 1, flag + MTOK, 0.15f);
    vq_rescue<<<1024, 256, 0, stream>>>(xr, cb1p, c2 + NTOK, cbs, keys, fc + 1, flag + MTOK, keys + MTOK);

    // indices + exact commit losses (overwrites dead xrh region with idxf -- safe)
    commit_idx_kernel<<<MTOK / 4, 256, 0, stream>>>(xr, cbs, cb1p, keys, keys + MTOK, idxf, idxi, slots);

    // quantized output [B,512,408] (overwrites dead r1h region -- safe)
    quant_out_kernel<<<dim3(NB, 7, 4), 256, 0, stream>>>(cbs, cb1p, idxi, qout);

    // decoder: d1 from code tables, then fused convT2+final+recon
    d1_gather_kernel<<<(MTOK * 128) / 256, 256, 0, stream>>>(P0, P1, idxi, bx1, h1);
    dec2_fused<<<M2TOK / 128, 256, 0, stream>>>(h1, Bd2, bx2, Wd3, bd3, img, out0, slots);

    finalize_kernel<<<1, 256, 0, stream>>>(slots, oscal);
}

// Round 13
// 1123.718 us; speedup vs baseline: 1.0763x; 1.0763x over previous
//
#include <hip/hip_runtime.h>

// ---------------- problem constants ----------------
#define NB    256
#define TLEN  1632
#define HIDC  64
#define CBD   512
#define NTOK  1024
#define T2L   816
#define T4L   408
#define MTOK  (NB*T4L)     // 104448
#define M2TOK (NB*T2L)     // 208896
#define MOUT  (NB*TLEN)    // 417792

// d_out flat offsets (floats)
#define DO_OUT    ((size_t)0)
#define DO_RECON  ((size_t)417792)
#define DO_IDX    ((size_t)417795)
#define DO_QUANT  ((size_t)626691)
// scratch inside d_out (dead until commit/quant_out): fp16 xr and fp16 q1-residual
#define DO_XRH    ((size_t)417796)                  // 16B-aligned; MTOK*256 f32-units
#define DO_R1H    (DO_XRH + (size_t)MTOK*256)       // ends 53,895,172 < 54,104,067

typedef unsigned short u16;
typedef unsigned long long u64;
typedef __attribute__((ext_vector_type(8))) short short8;
typedef __attribute__((ext_vector_type(4))) float f32x4;
typedef __attribute__((ext_vector_type(8))) _Float16 half8;
typedef __attribute__((ext_vector_type(4))) _Float16 half4;

// ---------------- workspace layout (float units) ----------------
static constexpr size_t OFF_XR  = 0;                         // MTOK*512 f32
static constexpr size_t OFF_H1  = OFF_XR + (size_t)MTOK*512;
static constexpr size_t OFF_H2  = OFF_H1 + (size_t)NB*T2L*64;
static constexpr size_t OFF_BE2 = OFF_H2 + (size_t)NB*T4L*64;
static constexpr size_t OFF_BD1 = OFF_BE2 + 8192;
static constexpr size_t OFF_BD2 = OFF_BD1 + 65536;
static constexpr size_t OFF_BX1 = OFF_BD2 + 8192;
static constexpr size_t OFF_BX2 = OFF_BX1 + 128;
static constexpr size_t OFF_ZB  = OFF_BX2 + 128;
static constexpr size_t OFF_C2  = OFF_ZB + 128;
static constexpr size_t OFF_SLOT= OFF_C2 + 2048;             // 1536 loss slots
static constexpr size_t OFF_IDXI= OFF_SLOT + 1536;
static constexpr size_t OFF_KEYS= OFF_IDXI + (size_t)MTOK*2;
static constexpr size_t OFF_FC  = OFF_KEYS + (size_t)MTOK*4;
static constexpr size_t OFF_FLAG= OFF_FC + 4;
static constexpr size_t OFF_CBH = OFF_FLAG + (size_t)MTOK*2; // 2048*512 u16 (fp16)
static constexpr size_t OFF_CBL = OFF_CBH + 524288;          // (unused)
static constexpr size_t OFF_P0  = OFF_CBL + 524288;
static constexpr size_t OFF_P1  = OFF_P0 + 131072;
static constexpr size_t OFF_PAIRS = OFF_P1 + 131072;         // MTOK*8 u64

// ---------------- helpers ----------------
__device__ inline u64 shfl_xor_u64_w16(u64 v, int m) {
    unsigned lo = (unsigned)v, hi = (unsigned)(v >> 32);
    lo = __shfl_xor(lo, m, 16);
    hi = __shfl_xor(hi, m, 16);
    return (((u64)hi) << 32) | lo;
}
__device__ inline u64 packkey(float d, int n) {
    unsigned u = __float_as_uint(d);
    u = (u & 0x80000000u) ? ~u : (u | 0x80000000u);
    return (((u64)u) << 32) | (unsigned)n;
}
__device__ inline float unpackd(u64 k) {
    unsigned u = (unsigned)(k >> 32);
    u = (u & 0x80000000u) ? (u & 0x7fffffffu) : ~u;
    return __uint_as_float(u);
}
__device__ inline void merge2(u64& k1, u64& k2, u64 o1, u64 o2) {
    u64 n1 = (k1 < o1) ? k1 : o1;
    u64 hi = (k1 < o1) ? o1 : k1;
    u64 cand = (k1 <= o1) ? k2 : o2;
    u64 n2 = (hi < cand) ? hi : cand;
    k1 = n1; k2 = n2;
}
__device__ inline half4 cvt_h4(float4 v) {
    half4 h;
    h.x = (_Float16)v.x; h.y = (_Float16)v.y;
    h.z = (_Float16)v.z; h.w = (_Float16)v.w;
    return h;
}
// async global->LDS copy, 16B per lane, dest = wave-uniform base + lane*16
__device__ inline void gll16(const u16* g, u16* l) {
    __builtin_amdgcn_global_load_lds((const __attribute__((address_space(1))) void*)g,
                                     (__attribute__((address_space(3))) void*)l, 16, 0, 0);
}

// ---------------- fused setup: weight prep + codebook fp16 + codebook norms ----------------
__global__ void setup_kernel(const float* __restrict__ We2, const float* __restrict__ Wtd1,
                             const float* __restrict__ Wtd2, const float* __restrict__ bd1,
                             const float* __restrict__ bd2, const float* __restrict__ cbs,
                             float* __restrict__ Be2, float* __restrict__ Bd1,
                             float* __restrict__ Bd2, float* __restrict__ bx1, float* __restrict__ bx2,
                             u16* __restrict__ cbh, float* __restrict__ c2) {
    size_t t = (size_t)blockIdx.x * 256 + threadIdx.x;   // grid 1024 -> 262144 threads
    {
        float4 v = *(const float4*)(cbs + t * 4);
        *(half4*)&cbh[t * 4] = cvt_h4(v);
    }
    {
        int w = (int)(t >> 6);
        int lane = threadIdx.x & 63;
        if (w < 2048) {
            const float* r = cbs + (size_t)w * 512;
            float4 a = *(const float4*)(r + lane * 8);
            float4 b = *(const float4*)(r + lane * 8 + 4);
            float s = a.x*a.x + a.y*a.y + a.z*a.z + a.w*a.w + b.x*b.x + b.y*b.y + b.z*b.z + b.w*b.w;
            #pragma unroll
            for (int o = 32; o > 0; o >>= 1) s += __shfl_down(s, o, 64);
            if (lane == 0) c2[w] = s;
        }
    }
    size_t stride = (size_t)gridDim.x * 256;
    for (size_t x = t; x < 64 * 128; x += stride) {
        int c = (int)(x >> 7), k = (int)(x & 127);
        Be2[x] = We2[c * 128 + ((k & 63) << 1) + (k >> 6)];
    }
    for (size_t x = t; x < 128 * 512; x += stride) {
        int n = (int)(x >> 9), k = (int)(x & 511);
        Bd1[x] = Wtd1[k * 128 + n];
    }
    for (size_t x = t; x < 128 * 64; x += stride) {
        int n = (int)(x >> 6), k = (int)(x & 63);
        Bd2[x] = Wtd2[k * 128 + n];
    }
    for (size_t x = t; x < 128; x += stride) { bx1[x] = bd1[x >> 1]; bx2[x] = bd2[x >> 1]; }
}

// ---------------- encoder conv1 ----------------
__global__ void enc1_kernel(const float* __restrict__ img, const float* __restrict__ W,
                            const float* __restrict__ bias, float* __restrict__ h1) {
    int idx = blockIdx.x * 256 + threadIdx.x;
    int c = idx & 63;
    int t = (idx >> 6) % T2L;
    int b = idx / (64 * T2L);
    float v = W[c * 2] * img[(size_t)b * TLEN + 2 * t] +
              W[c * 2 + 1] * img[(size_t)b * TLEN + 2 * t + 1] + bias[c];
    h1[idx] = fmaxf(v, 0.f);
}

// ---------------- generic NT SGEMM (cmode0 only); optional fp16 mirror of C ----------------
__global__ __launch_bounds__(256) void gemm_nt(const float* __restrict__ A, const float* __restrict__ Bw,
                        const float* __restrict__ bias, float* __restrict__ C,
                        int M, int N, int K, int amode, int relu, u16* __restrict__ xh) {
    __shared__ float As[32][132];
    __shared__ float Bs[32][68];
    int m0 = blockIdx.x * 128;
    int n0 = blockIdx.y * 64;
    int tid = threadIdx.x;
    int tx = tid & 15;
    int ty = tid >> 4;
    float acc[8][4];
    #pragma unroll
    for (int i = 0; i < 8; ++i)
        #pragma unroll
        for (int j = 0; j < 4; ++j) acc[i][j] = 0.f;

    for (int k0 = 0; k0 < K; k0 += 32) {
        #pragma unroll
        for (int i = 0; i < 4; ++i) {
            int idx = tid + i * 256;
            int row = idx >> 3;
            int kq = idx & 7;
            int m = m0 + row;
            size_t base;
            if (amode == 0) base = (size_t)m * K;
            else            base = (size_t)(((m / T4L) * T2L + 2 * (m % T4L)) * 64);
            float4 v = *(const float4*)(A + base + k0 + kq * 4);
            int kk = kq * 4;
            As[kk + 0][row] = v.x; As[kk + 1][row] = v.y;
            As[kk + 2][row] = v.z; As[kk + 3][row] = v.w;
        }
        #pragma unroll
        for (int i = 0; i < 2; ++i) {
            int idx = tid + i * 256;
            int row = idx >> 3;
            int kq = idx & 7;
            float4 v = *(const float4*)(Bw + (size_t)(n0 + row) * K + k0 + kq * 4);
            int kk = kq * 4;
            Bs[kk + 0][row] = v.x; Bs[kk + 1][row] = v.y;
            Bs[kk + 2][row] = v.z; Bs[kk + 3][row] = v.w;
        }
        __syncthreads();
        #pragma unroll
        for (int kk = 0; kk < 32; ++kk) {
            float a[8], bf[4];
            float4 a0 = *(const float4*)&As[kk][ty * 8];
            float4 a1 = *(const float4*)&As[kk][ty * 8 + 4];
            a[0]=a0.x; a[1]=a0.y; a[2]=a0.z; a[3]=a0.w;
            a[4]=a1.x; a[5]=a1.y; a[6]=a1.z; a[7]=a1.w;
            float4 b0 = *(const float4*)&Bs[kk][tx * 4];
            bf[0]=b0.x; bf[1]=b0.y; bf[2]=b0.z; bf[3]=b0.w;
            #pragma unroll
            for (int i = 0; i < 8; ++i)
                #pragma unroll
                for (int j = 0; j < 4; ++j) acc[i][j] += a[i] * bf[j];
        }
        __syncthreads();
    }
    #pragma unroll
    for (int i = 0; i < 8; ++i) {
        int m = m0 + ty * 8 + i;
        float4 v;
        v.x = acc[i][0] + bias[n0 + tx * 4 + 0];
        v.y = acc[i][1] + bias[n0 + tx * 4 + 1];
        v.z = acc[i][2] + bias[n0 + tx * 4 + 2];
        v.w = acc[i][3] + bias[n0 + tx * 4 + 3];
        if (relu) { v.x=fmaxf(v.x,0.f); v.y=fmaxf(v.y,0.f); v.z=fmaxf(v.z,0.f); v.w=fmaxf(v.w,0.f); }
        *(float4*)(C + (size_t)m * N + n0 + tx * 4) = v;
        if (xh) *(half4*)&xh[(size_t)m * N + n0 + tx * 4] = cvt_h4(v);
    }
}

// ---------------- VQ: 256x256 tile, 8 waves, quad-buffer + counted-vmcnt pipeline ----------------
// r11 verbatim (verified best: 213.5us): gll prefetch depth 2, 4 LDS buffers, raw s_barrier +
// literal s_waitcnt vmcnt(8/4/0) never 0 in steady state; XCD-bijective wg swizzle (1632=8*204);
// setprio around MFMA cluster; sched_barrier(0) pins ds_reads below the barrier.
__global__ __launch_bounds__(512, 2) void vq_f16_gll(
    const u16* __restrict__ Ah, const u16* __restrict__ cbh,
    const float* __restrict__ c2, u64* __restrict__ pairs)
{
    __shared__ __align__(16) u16 As[4][256 * 32];   // 64 KB
    __shared__ __align__(16) u16 Bs[4][256 * 32];   // 64 KB
    int tid = threadIdx.x;
    // XCD-aware bijective remap: f -> wg so each XCD (f%8) owns contiguous 204 wgs
    int f = blockIdx.y * 4 + blockIdx.x;
    int wg = (f & 7) * 204 + (f >> 3);
    int n0 = (wg & 3) * 256, m0 = (wg >> 2) * 256;
    int nblk = wg & 3;
    int lane = tid & 63, wid = tid >> 6;            // 8 waves
    int lm = lane & 15, quad = lane >> 4;
    int wm = wid >> 1, wn = wid & 1;                // 4x2 wave grid; wave tile 64(M) x 128(N)

    f32x4 acc[4][8];
    #pragma unroll
    for (int i = 0; i < 4; ++i)
        #pragma unroll
        for (int j = 0; j < 8; ++j) acc[i][j] = (f32x4){0.f, 0.f, 0.f, 0.f};

    // gll mapping: 16 1KB-segments per operand; wave w stages segments {w, w+8}.
    // Segment s covers rows s*16..s*16+15; lane l -> row s*16+(l>>2), chunk-slot l&3,
    // global chunk pre-swizzled: (l&3) ^ ((row>>1)&3). LDS dest wave-uniform s*512 (u16).
    int srow[2], schk[2];
    #pragma unroll
    for (int i = 0; i < 2; ++i) {
        int s = wid + i * 8;
        srow[i] = s * 16 + (lane >> 2);
        schk[i] = (lane & 3) ^ ((srow[i] >> 1) & 3);
    }

#define VQ_GLL(BUF, K0)                                                               \
    _Pragma("unroll")                                                                 \
    for (int i = 0; i < 2; ++i) {                                                     \
        int s = wid + i * 8;                                                          \
        gll16(Ah + (size_t)(m0 + srow[i]) * 512 + (K0) + schk[i] * 8,                 \
              &As[BUF][s * 512]);                                                     \
        gll16(cbh + (size_t)(n0 + srow[i]) * 512 + (K0) + schk[i] * 8,                \
              &Bs[BUF][s * 512]);                                                     \
    }

#define VQ_COMPUTE(BUF) {                                                             \
        half8 ah[4];                                                                  \
        _Pragma("unroll")                                                             \
        for (int mt = 0; mt < 4; ++mt) {                                              \
            int r = wm * 64 + mt * 16 + lm;                                           \
            ah[mt] = *(const half8*)&As[BUF][r * 32 + ((quad ^ ((r >> 1) & 3)) * 8)]; \
        }                                                                             \
        __builtin_amdgcn_s_setprio(1);                                                \
        _Pragma("unroll")                                                             \
        for (int nt = 0; nt < 8; ++nt) {                                              \
            int rn = wn * 128 + nt * 16 + lm;                                         \
            half8 bh = *(const half8*)&Bs[BUF][rn * 32 + ((quad ^ ((rn >> 1) & 3)) * 8)]; \
            _Pragma("unroll")                                                         \
            for (int mt = 0; mt < 4; ++mt)                                            \
                acc[mt][nt] = __builtin_amdgcn_mfma_f32_16x16x32_f16(ah[mt], bh, acc[mt][nt], 0, 0, 0); \
        }                                                                             \
        __builtin_amdgcn_s_setprio(0);                                                \
    }

    // prologue: batches 0,1 in flight (8 outstanding VMEM)
    VQ_GLL(0, 0);
    VQ_GLL(1, 32);
    #pragma unroll
    for (int t = 0; t < 16; ++t) {
        if (t + 2 < 16) VQ_GLL((t + 2) & 3, (t + 2) * 32);   // 4 more -> 12 outstanding
        // wait until batch t's 4 ops retired (in-order retirement, m135)
        if (t <= 13)      asm volatile("s_waitcnt vmcnt(8)" ::: "memory");
        else if (t == 14) asm volatile("s_waitcnt vmcnt(4)" ::: "memory");
        else              asm volatile("s_waitcnt vmcnt(0)" ::: "memory");
        __builtin_amdgcn_s_barrier();                         // everyone's batch t landed
        __builtin_amdgcn_sched_barrier(0);                    // pin ds_reads below barrier
        VQ_COMPUTE(t & 3);
    }
#undef VQ_GLL
#undef VQ_COMPUTE

    float c2v[8];
    #pragma unroll
    for (int nt = 0; nt < 8; ++nt) c2v[nt] = c2[n0 + wn * 128 + nt * 16 + lm];

    u64* scr = (u64*)&As[0][0];   // [2 wn][256 tokens][2] = 1024 u64 = 8KB (fits in As[0])
    #pragma unroll
    for (int mt = 0; mt < 4; ++mt) {
        #pragma unroll
        for (int rg = 0; rg < 4; ++rg) {
            int tl = wm * 64 + mt * 16 + quad * 4 + rg;
            u64 k1 = ~0ull, k2 = ~0ull;
            #pragma unroll
            for (int nt = 0; nt < 8; ++nt) {
                float d = c2v[nt] - 2.0f * acc[mt][nt][rg];
                u64 k = packkey(d, n0 + wn * 128 + nt * 16 + lm);
                if (k < k1) { k2 = k1; k1 = k; } else if (k < k2) { k2 = k; }
            }
            #pragma unroll
            for (int s = 1; s < 16; s <<= 1) {
                u64 o1 = shfl_xor_u64_w16(k1, s);
                u64 o2 = shfl_xor_u64_w16(k2, s);
                merge2(k1, k2, o1, o2);
            }
            if (lm == 0) { scr[wn * 512 + tl * 2] = k1; scr[wn * 512 + tl * 2 + 1] = k2; }
        }
    }
    __syncthreads();
    if (tid < 256) {
        u64 a1 = scr[tid * 2], a2 = scr[tid * 2 + 1];
        merge2(a1, a2, scr[512 + tid * 2], scr[512 + tid * 2 + 1]);
        size_t base = (size_t)(m0 + tid) * 8 + nblk * 2;
        pairs[base] = a1; pairs[base + 1] = a2;
    }
}

// ---------------- fused reduce + q1 residual prep (q0 path) ----------------
// 32-lane group per token: butterfly top-2 over the 8 pair slots (lanes 0-7), lane 0 writes
// key + flag; i0 broadcast via shfl; all 32 lanes emit r1h = xrh - cbh0[i0] (16 elems/lane).
// Values bit-identical to vq_reduce + r1_prep.
__global__ void vq_reduce_prep(const u64* __restrict__ pairs, u64* __restrict__ keybuf,
                               int* __restrict__ fc, int* __restrict__ flaglist, float tau,
                               const u16* __restrict__ xrh, const u16* __restrict__ cbh0,
                               u16* __restrict__ r1h) {
    int tid = threadIdx.x;
    int g = tid >> 5, l = tid & 31;
    int m = blockIdx.x * 8 + g;
    u64 k1 = ~0ull, k2 = ~0ull;
    if (l < 8) k1 = pairs[(size_t)m * 8 + l];
    #pragma unroll
    for (int s = 1; s < 8; s <<= 1) {
        u64 o1 = shfl_xor_u64_w16(k1, s);
        u64 o2 = shfl_xor_u64_w16(k2, s);
        merge2(k1, k2, o1, o2);
    }
    int i0 = (int)(k1 & 0xFFFFFFFFull);
    i0 = __shfl(i0, 0, 32);            // broadcast from lane 0 of each 32-group
    if (l == 0) {
        keybuf[m] = k1;
        if (unpackd(k2) - unpackd(k1) < tau) {
            int pos = atomicAdd(fc, 1);
            flaglist[pos] = m;
        }
    }
    const half8* xp = (const half8*)(xrh + (size_t)m * 512 + l * 16);
    const half8* cp = (const half8*)(cbh0 + (size_t)i0 * 512 + l * 16);
    half8* rp = (half8*)(r1h + (size_t)m * 512 + l * 16);
    rp[0] = xp[0] - cp[0];
    rp[1] = xp[1] - cp[1];
}

// ---------------- reduce: global top2 per token from 4 block-pairs (q1 path) ----------------
__global__ void vq_reduce(const u64* __restrict__ pairs, u64* __restrict__ keybuf,
                          int* __restrict__ fc, int* __restrict__ flaglist, float tau) {
    int m = blockIdx.x * 256 + threadIdx.x;
    const u64* p = pairs + (size_t)m * 8;
    u64 k1 = ~0ull, k2 = ~0ull;
    #pragma unroll
    for (int i = 0; i < 8; ++i) {
        u64 k = p[i];
        if (k < k1) { k2 = k1; k1 = k; } else if (k < k2) { k2 = k; }
    }
    keybuf[m] = k1;
    if (unpackd(k2) - unpackd(k1) < tau) {
        int pos = atomicAdd(fc, 1);
        flaglist[pos] = m;
    }
}

// ---------------- rescue: exact fp32 argmin for flagged tokens ----
__global__ void vq_rescue(const float* __restrict__ xr, const float* __restrict__ cb,
                          const float* __restrict__ c2, const float* __restrict__ cb0,
                          const u64* __restrict__ prevkeys,
                          const int* __restrict__ fc, const int* __restrict__ flaglist,
                          u64* __restrict__ keybuf) {
    __shared__ u64 red[4];
    int cnt = *fc;
    int lane = threadIdx.x & 63, wid = threadIdx.x >> 6;
    for (int f = blockIdx.x; f < cnt; f += gridDim.x) {
        int m = flaglist[f];
        float4 rv0 = *(const float4*)(xr + (size_t)m * 512 + lane * 8);
        float4 rv1 = *(const float4*)(xr + (size_t)m * 512 + lane * 8 + 4);
        if (cb0) {
            size_t co = (size_t)(prevkeys[m] & 0xFFFFFFFFull) * 512;
            float4 c0 = *(const float4*)(cb0 + co + lane * 8);
            float4 c1 = *(const float4*)(cb0 + co + lane * 8 + 4);
            rv0.x -= c0.x; rv0.y -= c0.y; rv0.z -= c0.z; rv0.w -= c0.w;
            rv1.x -= c1.x; rv1.y -= c1.y; rv1.z -= c1.z; rv1.w -= c1.w;
        }
        u64 best = ~0ull;
        for (int c = wid * 256; c < wid * 256 + 256; ++c) {
            const float* cp = cb + (size_t)c * 512 + lane * 8;
            float4 c0 = *(const float4*)cp;
            float4 c1 = *(const float4*)(cp + 4);
            float p = rv0.x*c0.x + rv0.y*c0.y + rv0.z*c0.z + rv0.w*c0.w
                    + rv1.x*c1.x + rv1.y*c1.y + rv1.z*c1.z + rv1.w*c1.w;
            #pragma unroll
            for (int s = 1; s < 64; s <<= 1) p += __shfl_xor(p, s, 64);
            u64 k = packkey(c2[c] - 2.0f * p, c);
            if (k < best) best = k;
        }
        if (lane == 0) red[wid] = best;
        __syncthreads();
        if (threadIdx.x == 0) {
            u64 b = red[0];
            if (red[1] < b) b = red[1];
            if (red[2] < b) b = red[2];
            if (red[3] < b) b = red[3];
            keybuf[m] = b;
        }
        __syncthreads();
    }
}

// ---------------- commit + indices (wave per token, exact fp32 losses) ----------------
__global__ void commit_idx_kernel(const float* __restrict__ xr,
                                  const float* __restrict__ cb0f, const float* __restrict__ cb1f,
                                  const u64* __restrict__ keys0, const u64* __restrict__ keys1,
                                  float* __restrict__ idx_f, int* __restrict__ idx_i,
                                  float* __restrict__ slots) {
    int tid = threadIdx.x;
    int lane = tid & 63;
    int m = blockIdx.x * 4 + (tid >> 6);
    unsigned i0 = (unsigned)(keys0[m] & 0xFFFFFFFFull);
    unsigned i1 = (unsigned)(keys1[m] & 0xFFFFFFFFull);
    const float* x = xr + (size_t)m * 512 + lane * 8;
    const float* c0 = cb0f + (size_t)i0 * 512 + lane * 8;
    const float* c1 = cb1f + (size_t)i1 * 512 + lane * 8;
    float4 x0 = *(const float4*)x, x1 = *(const float4*)(x + 4);
    float4 a0 = *(const float4*)c0, a1 = *(const float4*)(c0 + 4);
    float4 b0 = *(const float4*)c1, b1 = *(const float4*)(c1 + 4);
    x0.x -= a0.x; x0.y -= a0.y; x0.z -= a0.z; x0.w -= a0.w;
    x1.x -= a1.x; x1.y -= a1.y; x1.z -= a1.z; x1.w -= a1.w;
    float s1 = x0.x*x0.x + x0.y*x0.y + x0.z*x0.z + x0.w*x0.w
             + x1.x*x1.x + x1.y*x1.y + x1.z*x1.z + x1.w*x1.w;
    x0.x -= b0.x; x0.y -= b0.y; x0.z -= b0.z; x0.w -= b0.w;
    x1.x -= b1.x; x1.y -= b1.y; x1.z -= b1.z; x1.w -= b1.w;
    float s2 = x0.x*x0.x + x0.y*x0.y + x0.z*x0.z + x0.w*x0.w
             + x1.x*x1.x + x1.y*x1.y + x1.z*x1.z + x1.w*x1.w;
    #pragma unroll
    for (int o = 32; o > 0; o >>= 1) { s1 += __shfl_down(s1, o, 64); s2 += __shfl_down(s2, o, 64); }
    if (lane == 0) {
        atomicAdd(&slots[512 + (m & 511)], s1);
        atomicAdd(&slots[1024 + (m & 511)], s2);
        idx_f[(size_t)m * 2]     = (float)i0;
        idx_f[(size_t)m * 2 + 1] = (float)i1;
        idx_i[m * 2] = (int)i0;
        idx_i[m * 2 + 1] = (int)i1;
    }
}

// ---------------- quantized output (channel-major) via LDS transpose ----------------
__global__ void quant_out_kernel(const float* __restrict__ cb0, const float* __restrict__ cb1,
                                 const int* __restrict__ idxi, float* __restrict__ out4) {
    __shared__ float buf[64][129];
    __shared__ int i0s[64], i1s[64];
    int b = blockIdx.x;
    int t0 = blockIdx.y * 64;
    int c0 = blockIdx.z * 128;
    int tid = threadIdx.x;
    if (tid < 64) {
        int t = t0 + tid;
        int i0 = 0, i1 = 0;
        if (t < T4L) { i0 = idxi[(b * T4L + t) * 2]; i1 = idxi[(b * T4L + t) * 2 + 1]; }
        i0s[tid] = i0; i1s[tid] = i1;
    }
    __syncthreads();
    int cl = tid & 127, th = tid >> 7;
    for (int t = th; t < 64; t += 2) {
        if (t0 + t < T4L)
            buf[t][cl] = cb0[(size_t)i0s[t] * 512 + c0 + cl] + cb1[(size_t)i1s[t] * 512 + c0 + cl];
    }
    __syncthreads();
    int lane = tid & 63, ch = tid >> 6;
    for (int cc = ch; cc < 128; cc += 4) {
        int t = t0 + lane;
        if (t < T4L) out4[((size_t)b * 512 + c0 + cc) * T4L + t] = buf[lane][cc];
    }
}

// ---------------- decoder stage-1 via code tables ----------------
__global__ void d1_gather_kernel(const float* __restrict__ P0, const float* __restrict__ P1,
                                 const int* __restrict__ idxi, const float* __restrict__ bx1,
                                 float* __restrict__ d1) {
    int x = blockIdx.x * 256 + threadIdx.x;
    int n = x & 127;
    int m = x >> 7;
    int b = m / T4L, t = m % T4L;
    int i0 = idxi[m * 2], i1 = idxi[m * 2 + 1];
    float v = P0[i0 * 128 + n] + P1[i1 * 128 + n] + bx1[n];
    v = fmaxf(v, 0.f);
    d1[((size_t)(b * T2L + 2 * t + (n & 1))) * 64 + (n >> 1)] = v;
}

// ---------------- fused convT2 + final 1x1 conv + recon loss ----------------
__global__ __launch_bounds__(256) void dec2_fused(
    const float* __restrict__ d1, const float* __restrict__ Bd2, const float* __restrict__ bx2,
    const float* __restrict__ W3, const float* __restrict__ b3, const float* __restrict__ img,
    float* __restrict__ out, float* __restrict__ slots)
{
    __shared__ float As[32][132];
    __shared__ float Bs[32][132];
    __shared__ float w3s[64];
    int m0 = blockIdx.x * 128;
    int tid = threadIdx.x;
    int tx = tid & 15;
    int ty = tid >> 4;
    if (tid < 64) w3s[tid] = W3[tid];
    float acc[8][8];
    #pragma unroll
    for (int i = 0; i < 8; ++i)
        #pragma unroll
        for (int j = 0; j < 8; ++j) acc[i][j] = 0.f;

    for (int k0 = 0; k0 < 64; k0 += 32) {
        #pragma unroll
        for (int i = 0; i < 4; ++i) {
            int idx = tid + i * 256;
            int row = idx >> 3;
            int kq = idx & 7;
            float4 v = *(const float4*)(d1 + (size_t)(m0 + row) * 64 + k0 + kq * 4);
            int kk = kq * 4;
            As[kk + 0][row] = v.x; As[kk + 1][row] = v.y;
            As[kk + 2][row] = v.z; As[kk + 3][row] = v.w;
        }
        #pragma unroll
        for (int i = 0; i < 4; ++i) {
            int idx = tid + i * 256;
            int row = idx >> 3;
            int kq = idx & 7;
            float4 v = *(const float4*)(Bd2 + (size_t)row * 64 + k0 + kq * 4);
            int kk = kq * 4;
            Bs[kk + 0][row] = v.x; Bs[kk + 1][row] = v.y;
            Bs[kk + 2][row] = v.z; Bs[kk + 3][row] = v.w;
        }
        __syncthreads();
        #pragma unroll
        for (int kk = 0; kk < 32; ++kk) {
            float a[8], bf[8];
            float4 a0 = *(const float4*)&As[kk][ty * 8];
            float4 a1 = *(const float4*)&As[kk][ty * 8 + 4];
            a[0]=a0.x; a[1]=a0.y; a[2]=a0.z; a[3]=a0.w;
            a[4]=a1.x; a[5]=a1.y; a[6]=a1.z; a[7]=a1.w;
            float4 b0 = *(const float4*)&Bs[kk][tx * 4];
            float4 b1 = *(const float4*)&Bs[kk][64 + tx * 4];
            bf[0]=b0.x; bf[1]=b0.y; bf[2]=b0.z; bf[3]=b0.w;
            bf[4]=b1.x; bf[5]=b1.y; bf[6]=b1.z; bf[7]=b1.w;
            #pragma unroll
            for (int i = 0; i < 8; ++i)
                #pragma unroll
                for (int j = 0; j < 8; ++j) acc[i][j] += a[i] * bf[j];
        }
        __syncthreads();
    }
    float bb3 = b3[0];
    float local = 0.f;
    #pragma unroll
    for (int i = 0; i < 8; ++i) {
        float s0 = 0.f, s1 = 0.f;
        #pragma unroll
        for (int j = 0; j < 4; ++j) {
            int n = tx * 4 + j;
            float v = fmaxf(acc[i][j] + bx2[n], 0.f);
            float w = w3s[n >> 1];
            if (j & 1) s1 += w * v; else s0 += w * v;
            int n2 = 64 + tx * 4 + j;
            float v2 = fmaxf(acc[i][j + 4] + bx2[n2], 0.f);
            float w2 = w3s[n2 >> 1];
            if (j & 1) s1 += w2 * v2; else s0 += w2 * v2;
        }
        #pragma unroll
        for (int o = 8; o > 0; o >>= 1) { s0 += __shfl_down(s0, o, 16); s1 += __shfl_down(s1, o, 16); }
        if (tx == 0) {
            int m = m0 + ty * 8 + i;
            int b = m / T2L, t2 = m % T2L;
            size_t o0 = (size_t)b * TLEN + 2 * t2;
            float v0 = s0 + bb3, v1 = s1 + bb3;
            out[o0] = v0; out[o0 + 1] = v1;
            float e0 = img[o0] - v0, e1 = img[o0 + 1] - v1;
            local += e0 * e0 + e1 * e1;
        }
    }
    if (tx == 0) atomicAdd(&slots[(blockIdx.x * 16 + ty) & 511], local);
}

// ---------------- finalize losses ----------------
__global__ void finalize_kernel(const float* __restrict__ slots, float* __restrict__ out_scalars) {
    __shared__ float red[256];
    int tid = threadIdx.x;
    for (int which = 0; which < 3; ++which) {
        float s = slots[which * 512 + tid] + slots[which * 512 + tid + 256];
        red[tid] = s; __syncthreads();
        for (int st = 128; st > 0; st >>= 1) { if (tid < st) red[tid] += red[tid + st]; __syncthreads(); }
        if (tid == 0) {
            float denom = (which == 0) ? (float)MOUT : (float)((size_t)MTOK * 512);
            out_scalars[which] = red[0] / denom;
        }
        __syncthreads();
    }
}

// ---------------- launch ----------------
extern "C" void kernel_launch(void* const* d_in, const int* in_sizes, int n_in,
                              void* d_out, int out_size, void* d_ws, size_t ws_size,
                              hipStream_t stream) {
    const float* img  = (const float*)d_in[0];
    const float* We1  = (const float*)d_in[1];
    const float* be1  = (const float*)d_in[2];
    const float* We2  = (const float*)d_in[3];
    const float* be2  = (const float*)d_in[4];
    const float* We3  = (const float*)d_in[5];
    const float* be3  = (const float*)d_in[6];
    const float* cbs  = (const float*)d_in[7];
    const float* Wtd1 = (const float*)d_in[8];
    const float* bd1  = (const float*)d_in[9];
    const float* Wtd2 = (const float*)d_in[10];
    const float* bd2  = (const float*)d_in[11];
    const float* Wd3  = (const float*)d_in[12];
    const float* bd3  = (const float*)d_in[13];

    float* w = (float*)d_ws;
    float* xr   = w + OFF_XR;
    float* h1   = w + OFF_H1;
    float* h2   = w + OFF_H2;
    float* Be2  = w + OFF_BE2;
    float* Bd1  = w + OFF_BD1;
    float* Bd2  = w + OFF_BD2;
    float* bx1  = w + OFF_BX1;
    float* bx2  = w + OFF_BX2;
    float* zerob= w + OFF_ZB;
    float* c2   = w + OFF_C2;
    float* slots= w + OFF_SLOT;
    int*   idxi = (int*)(w + OFF_IDXI);
    u64*   keys = (u64*)(w + OFF_KEYS);
    int*   fc   = (int*)(w + OFF_FC);
    int*   flag = (int*)(w + OFF_FLAG);
    u16*   cbh  = (u16*)(w + OFF_CBH);
    float* P0   = w + OFF_P0;
    float* P1   = w + OFF_P1;
    u64*   pairs= (u64*)(w + OFF_PAIRS);

    float* outp = (float*)d_out;
    float* out0   = outp + DO_OUT;
    float* oscal  = outp + DO_RECON;
    float* idxf   = outp + DO_IDX;
    float* qout   = outp + DO_QUANT;
    // d_out scratch (dead until commit/quant_out, which run after all consumers):
    u16*   xrh    = (u16*)(outp + DO_XRH);
    u16*   r1h    = (u16*)(outp + DO_R1H);

    hipMemsetAsync(slots, 0, 1536 * sizeof(float), stream);
    hipMemsetAsync(fc, 0, 2 * sizeof(int), stream);
    hipMemsetAsync(zerob, 0, 128 * sizeof(float), stream);

    setup_kernel<<<1024, 256, 0, stream>>>(We2, Wtd1, Wtd2, bd1, bd2, cbs,
                                           Be2, Bd1, Bd2, bx1, bx2, cbh, c2);

    const float* cb1p = cbs + (size_t)NTOK * CBD;

    // decoder stage-1 code tables: P = cb . Bd1^T  (P0,P1 contiguous -> single M=2048 gemm)
    gemm_nt<<<dim3(16, 2), 256, 0, stream>>>(cbs, Bd1, zerob, P0, 2048, 128, 512, 0, 0, nullptr);

    // encoder
    enc1_kernel<<<(NB * T2L * HIDC) / 256, 256, 0, stream>>>(img, We1, be1, h1);
    gemm_nt<<<dim3(MTOK / 128, 1), 256, 0, stream>>>(h1, Be2, be2, h2, MTOK, 64, 128, 1, 1, nullptr);
    gemm_nt<<<dim3(MTOK / 128, 8), 256, 0, stream>>>(h2, We3, be3, xr, MTOK, 512, 64, 0, 0, xrh);

    // residual VQ, q = 0: pipelined pure-gll fp16 MFMA, TAU 0.05
    vq_f16_gll<<<dim3(4, MTOK / 256), 512, 0, stream>>>(xrh, cbh, c2, pairs);
    // fused reduce + r1h prep (bit-identical to vq_reduce + r1_prep)
    vq_reduce_prep<<<MTOK / 8, 256, 0, stream>>>(pairs, keys, fc + 0, flag, 0.05f, xrh, cbh, r1h);
    vq_rescue<<<1024, 256, 0, stream>>>(xr, cbs, c2, nullptr, nullptr, fc + 0, flag, keys);
    // q = 1: TAU 0.15
    vq_f16_gll<<<dim3(4, MTOK / 256), 512, 0, stream>>>(r1h, cbh + (size_t)NTOK * 512, c2 + NTOK, pairs);
    vq_reduce<<<MTOK / 256, 256, 0, stream>>>(pairs, keys + MTOK, fc + 1, flag + MTOK, 0.15f);
    vq_rescue<<<1024, 256, 0, stream>>>(xr, cb1p, c2 + NTOK, cbs, keys, fc + 1, flag + MTOK, keys + MTOK);

    // indices + exact commit losses (overwrites dead xrh region with idxf -- safe)
    commit_idx_kernel<<<MTOK / 4, 256, 0, stream>>>(xr, cbs, cb1p, keys, keys + MTOK, idxf, idxi, slots);

    // quantized output [B,512,408] (overwrites dead r1h region -- safe)
    quant_out_kernel<<<dim3(NB, 7, 4), 256, 0, stream>>>(cbs, cb1p, idxi, qout);

    // decoder: d1 from code tables, then fused convT2+final+recon
    d1_gather_kernel<<<(MTOK * 128) / 256, 256, 0, stream>>>(P0, P1, idxi, bx1, h1);
    dec2_fused<<<M2TOK / 128, 256, 0, stream>>>(h1, Bd2, bx2, Wd3, bd3, img, out0, slots);

    finalize_kernel<<<1, 256, 0, stream>>>(slots, oscal);
}

// Round 14
// 1085.787 us; speedup vs baseline: 1.1139x; 1.0349x over previous
//
#include <hip/hip_runtime.h>

// ---------------- problem constants ----------------
#define NB    256
#define TLEN  1632
#define HIDC  64
#define CBD   512
#define NTOK  1024
#define T2L   816
#define T4L   408
#define MTOK  (NB*T4L)     // 104448
#define M2TOK (NB*T2L)     // 208896
#define MOUT  (NB*TLEN)    // 417792

// d_out flat offsets (floats)
#define DO_OUT    ((size_t)0)
#define DO_RECON  ((size_t)417792)
#define DO_IDX    ((size_t)417795)
#define DO_QUANT  ((size_t)626691)
// scratch inside d_out (dead until commit/quant_out): fp16 xr and fp16 q1-residual
#define DO_XRH    ((size_t)417796)                  // 16B-aligned; MTOK*256 f32-units
#define DO_R1H    (DO_XRH + (size_t)MTOK*256)       // ends 53,895,172 < 54,104,067

typedef unsigned short u16;
typedef unsigned long long u64;
typedef __attribute__((ext_vector_type(8))) short short8;
typedef __attribute__((ext_vector_type(4))) float f32x4;
typedef __attribute__((ext_vector_type(8))) _Float16 half8;
typedef __attribute__((ext_vector_type(4))) _Float16 half4;

// ---------------- workspace layout (float units) ----------------
static constexpr size_t OFF_XR  = 0;                         // MTOK*512 f32
static constexpr size_t OFF_H1  = OFF_XR + (size_t)MTOK*512;
static constexpr size_t OFF_H2  = OFF_H1 + (size_t)NB*T2L*64;
static constexpr size_t OFF_BE2 = OFF_H2 + (size_t)NB*T4L*64;
static constexpr size_t OFF_BD1 = OFF_BE2 + 8192;
static constexpr size_t OFF_BD2 = OFF_BD1 + 65536;
static constexpr size_t OFF_BX1 = OFF_BD2 + 8192;
static constexpr size_t OFF_BX2 = OFF_BX1 + 128;
static constexpr size_t OFF_ZB  = OFF_BX2 + 128;
static constexpr size_t OFF_C2  = OFF_ZB + 128;
static constexpr size_t OFF_SLOT= OFF_C2 + 2048;             // 1536 loss slots
static constexpr size_t OFF_IDXI= OFF_SLOT + 1536;
static constexpr size_t OFF_KEYS= OFF_IDXI + (size_t)MTOK*2;
static constexpr size_t OFF_FC  = OFF_KEYS + (size_t)MTOK*4;
static constexpr size_t OFF_FLAG= OFF_FC + 4;
static constexpr size_t OFF_CBH = OFF_FLAG + (size_t)MTOK*2; // 2048*512 u16 (fp16)
static constexpr size_t OFF_CBL = OFF_CBH + 524288;          // (unused)
static constexpr size_t OFF_P0  = OFF_CBL + 524288;
static constexpr size_t OFF_P1  = OFF_P0 + 131072;
static constexpr size_t OFF_PAIRS = OFF_P1 + 131072;         // MTOK*8 u64

// ---------------- helpers ----------------
__device__ inline u64 shfl_xor_u64_w16(u64 v, int m) {
    unsigned lo = (unsigned)v, hi = (unsigned)(v >> 32);
    lo = __shfl_xor(lo, m, 16);
    hi = __shfl_xor(hi, m, 16);
    return (((u64)hi) << 32) | lo;
}
__device__ inline u64 packkey(float d, int n) {
    unsigned u = __float_as_uint(d);
    u = (u & 0x80000000u) ? ~u : (u | 0x80000000u);
    return (((u64)u) << 32) | (unsigned)n;
}
__device__ inline float unpackd(u64 k) {
    unsigned u = (unsigned)(k >> 32);
    u = (u & 0x80000000u) ? (u & 0x7fffffffu) : ~u;
    return __uint_as_float(u);
}
__device__ inline void merge2(u64& k1, u64& k2, u64 o1, u64 o2) {
    u64 n1 = (k1 < o1) ? k1 : o1;
    u64 hi = (k1 < o1) ? o1 : k1;
    u64 cand = (k1 <= o1) ? k2 : o2;
    u64 n2 = (hi < cand) ? hi : cand;
    k1 = n1; k2 = n2;
}
__device__ inline half4 cvt_h4(float4 v) {
    half4 h;
    h.x = (_Float16)v.x; h.y = (_Float16)v.y;
    h.z = (_Float16)v.z; h.w = (_Float16)v.w;
    return h;
}
// async global->LDS copy, 16B per lane, dest = wave-uniform base + lane*16
__device__ inline void gll16(const u16* g, u16* l) {
    __builtin_amdgcn_global_load_lds((const __attribute__((address_space(1))) void*)g,
                                     (__attribute__((address_space(3))) void*)l, 16, 0, 0);
}

// ---------------- fused setup: weight prep + codebook fp16 + codebook norms ----------------
__global__ void setup_kernel(const float* __restrict__ We2, const float* __restrict__ Wtd1,
                             const float* __restrict__ Wtd2, const float* __restrict__ bd1,
                             const float* __restrict__ bd2, const float* __restrict__ cbs,
                             float* __restrict__ Be2, float* __restrict__ Bd1,
                             float* __restrict__ Bd2, float* __restrict__ bx1, float* __restrict__ bx2,
                             u16* __restrict__ cbh, float* __restrict__ c2) {
    size_t t = (size_t)blockIdx.x * 256 + threadIdx.x;   // grid 1024 -> 262144 threads
    {
        float4 v = *(const float4*)(cbs + t * 4);
        *(half4*)&cbh[t * 4] = cvt_h4(v);
    }
    {
        int w = (int)(t >> 6);
        int lane = threadIdx.x & 63;
        if (w < 2048) {
            const float* r = cbs + (size_t)w * 512;
            float4 a = *(const float4*)(r + lane * 8);
            float4 b = *(const float4*)(r + lane * 8 + 4);
            float s = a.x*a.x + a.y*a.y + a.z*a.z + a.w*a.w + b.x*b.x + b.y*b.y + b.z*b.z + b.w*b.w;
            #pragma unroll
            for (int o = 32; o > 0; o >>= 1) s += __shfl_down(s, o, 64);
            if (lane == 0) c2[w] = s;
        }
    }
    size_t stride = (size_t)gridDim.x * 256;
    for (size_t x = t; x < 64 * 128; x += stride) {
        int c = (int)(x >> 7), k = (int)(x & 127);
        Be2[x] = We2[c * 128 + ((k & 63) << 1) + (k >> 6)];
    }
    for (size_t x = t; x < 128 * 512; x += stride) {
        int n = (int)(x >> 9), k = (int)(x & 511);
        Bd1[x] = Wtd1[k * 128 + n];
    }
    for (size_t x = t; x < 128 * 64; x += stride) {
        int n = (int)(x >> 6), k = (int)(x & 63);
        Bd2[x] = Wtd2[k * 128 + n];
    }
    for (size_t x = t; x < 128; x += stride) { bx1[x] = bd1[x >> 1]; bx2[x] = bd2[x >> 1]; }
}

// ---------------- encoder conv1 ----------------
__global__ void enc1_kernel(const float* __restrict__ img, const float* __restrict__ W,
                            const float* __restrict__ bias, float* __restrict__ h1) {
    int idx = blockIdx.x * 256 + threadIdx.x;
    int c = idx & 63;
    int t = (idx >> 6) % T2L;
    int b = idx / (64 * T2L);
    float v = W[c * 2] * img[(size_t)b * TLEN + 2 * t] +
              W[c * 2 + 1] * img[(size_t)b * TLEN + 2 * t + 1] + bias[c];
    h1[idx] = fmaxf(v, 0.f);
}

// ---------------- generic NT SGEMM (cmode0 only); optional fp16 mirror of C ----------------
__global__ __launch_bounds__(256) void gemm_nt(const float* __restrict__ A, const float* __restrict__ Bw,
                        const float* __restrict__ bias, float* __restrict__ C,
                        int M, int N, int K, int amode, int relu, u16* __restrict__ xh) {
    __shared__ float As[32][132];
    __shared__ float Bs[32][68];
    int m0 = blockIdx.x * 128;
    int n0 = blockIdx.y * 64;
    int tid = threadIdx.x;
    int tx = tid & 15;
    int ty = tid >> 4;
    float acc[8][4];
    #pragma unroll
    for (int i = 0; i < 8; ++i)
        #pragma unroll
        for (int j = 0; j < 4; ++j) acc[i][j] = 0.f;

    for (int k0 = 0; k0 < K; k0 += 32) {
        #pragma unroll
        for (int i = 0; i < 4; ++i) {
            int idx = tid + i * 256;
            int row = idx >> 3;
            int kq = idx & 7;
            int m = m0 + row;
            size_t base;
            if (amode == 0) base = (size_t)m * K;
            else            base = (size_t)(((m / T4L) * T2L + 2 * (m % T4L)) * 64);
            float4 v = *(const float4*)(A + base + k0 + kq * 4);
            int kk = kq * 4;
            As[kk + 0][row] = v.x; As[kk + 1][row] = v.y;
            As[kk + 2][row] = v.z; As[kk + 3][row] = v.w;
        }
        #pragma unroll
        for (int i = 0; i < 2; ++i) {
            int idx = tid + i * 256;
            int row = idx >> 3;
            int kq = idx & 7;
            float4 v = *(const float4*)(Bw + (size_t)(n0 + row) * K + k0 + kq * 4);
            int kk = kq * 4;
            Bs[kk + 0][row] = v.x; Bs[kk + 1][row] = v.y;
            Bs[kk + 2][row] = v.z; Bs[kk + 3][row] = v.w;
        }
        __syncthreads();
        #pragma unroll
        for (int kk = 0; kk < 32; ++kk) {
            float a[8], bf[4];
            float4 a0 = *(const float4*)&As[kk][ty * 8];
            float4 a1 = *(const float4*)&As[kk][ty * 8 + 4];
            a[0]=a0.x; a[1]=a0.y; a[2]=a0.z; a[3]=a0.w;
            a[4]=a1.x; a[5]=a1.y; a[6]=a1.z; a[7]=a1.w;
            float4 b0 = *(const float4*)&Bs[kk][tx * 4];
            bf[0]=b0.x; bf[1]=b0.y; bf[2]=b0.z; bf[3]=b0.w;
            #pragma unroll
            for (int i = 0; i < 8; ++i)
                #pragma unroll
                for (int j = 0; j < 4; ++j) acc[i][j] += a[i] * bf[j];
        }
        __syncthreads();
    }
    #pragma unroll
    for (int i = 0; i < 8; ++i) {
        int m = m0 + ty * 8 + i;
        float4 v;
        v.x = acc[i][0] + bias[n0 + tx * 4 + 0];
        v.y = acc[i][1] + bias[n0 + tx * 4 + 1];
        v.z = acc[i][2] + bias[n0 + tx * 4 + 2];
        v.w = acc[i][3] + bias[n0 + tx * 4 + 3];
        if (relu) { v.x=fmaxf(v.x,0.f); v.y=fmaxf(v.y,0.f); v.z=fmaxf(v.z,0.f); v.w=fmaxf(v.w,0.f); }
        *(float4*)(C + (size_t)m * N + n0 + tx * 4) = v;
        if (xh) *(half4*)&xh[(size_t)m * N + n0 + tx * 4] = cvt_h4(v);
    }
}

// ---------------- VQ: 256x256 tile, 8 waves, quad-buffer + counted-vmcnt pipeline ----------------
// r13 structure (verified best: 209us) minus setprio (m190: setprio hurts lockstep barrier-synced
// waves -- our regime). gll prefetch depth 2 (max race-safe depth at 4 buffers), raw s_barrier +
// literal s_waitcnt vmcnt(8/4/0) never 0 in steady state; XCD-bijective wg swizzle (1632=8*204);
// sched_barrier(0) pins ds_reads below the barrier (cross-wave visibility of gll writes).
__global__ __launch_bounds__(512, 2) void vq_f16_gll(
    const u16* __restrict__ Ah, const u16* __restrict__ cbh,
    const float* __restrict__ c2, u64* __restrict__ pairs)
{
    __shared__ __align__(16) u16 As[4][256 * 32];   // 64 KB
    __shared__ __align__(16) u16 Bs[4][256 * 32];   // 64 KB
    int tid = threadIdx.x;
    // XCD-aware bijective remap: f -> wg so each XCD (f%8) owns contiguous 204 wgs
    int f = blockIdx.y * 4 + blockIdx.x;
    int wg = (f & 7) * 204 + (f >> 3);
    int n0 = (wg & 3) * 256, m0 = (wg >> 2) * 256;
    int nblk = wg & 3;
    int lane = tid & 63, wid = tid >> 6;            // 8 waves
    int lm = lane & 15, quad = lane >> 4;
    int wm = wid >> 1, wn = wid & 1;                // 4x2 wave grid; wave tile 64(M) x 128(N)

    f32x4 acc[4][8];
    #pragma unroll
    for (int i = 0; i < 4; ++i)
        #pragma unroll
        for (int j = 0; j < 8; ++j) acc[i][j] = (f32x4){0.f, 0.f, 0.f, 0.f};

    // gll mapping: 16 1KB-segments per operand; wave w stages segments {w, w+8}.
    // Segment s covers rows s*16..s*16+15; lane l -> row s*16+(l>>2), chunk-slot l&3,
    // global chunk pre-swizzled: (l&3) ^ ((row>>1)&3). LDS dest wave-uniform s*512 (u16).
    int srow[2], schk[2];
    #pragma unroll
    for (int i = 0; i < 2; ++i) {
        int s = wid + i * 8;
        srow[i] = s * 16 + (lane >> 2);
        schk[i] = (lane & 3) ^ ((srow[i] >> 1) & 3);
    }

#define VQ_GLL(BUF, K0)                                                               \
    _Pragma("unroll")                                                                 \
    for (int i = 0; i < 2; ++i) {                                                     \
        int s = wid + i * 8;                                                          \
        gll16(Ah + (size_t)(m0 + srow[i]) * 512 + (K0) + schk[i] * 8,                 \
              &As[BUF][s * 512]);                                                     \
        gll16(cbh + (size_t)(n0 + srow[i]) * 512 + (K0) + schk[i] * 8,                \
              &Bs[BUF][s * 512]);                                                     \
    }

#define VQ_COMPUTE(BUF) {                                                             \
        half8 ah[4];                                                                  \
        _Pragma("unroll")                                                             \
        for (int mt = 0; mt < 4; ++mt) {                                              \
            int r = wm * 64 + mt * 16 + lm;                                           \
            ah[mt] = *(const half8*)&As[BUF][r * 32 + ((quad ^ ((r >> 1) & 3)) * 8)]; \
        }                                                                             \
        _Pragma("unroll")                                                             \
        for (int nt = 0; nt < 8; ++nt) {                                              \
            int rn = wn * 128 + nt * 16 + lm;                                         \
            half8 bh = *(const half8*)&Bs[BUF][rn * 32 + ((quad ^ ((rn >> 1) & 3)) * 8)]; \
            _Pragma("unroll")                                                         \
            for (int mt = 0; mt < 4; ++mt)                                            \
                acc[mt][nt] = __builtin_amdgcn_mfma_f32_16x16x32_f16(ah[mt], bh, acc[mt][nt], 0, 0, 0); \
        }                                                                             \
    }

    // prologue: batches 0,1 in flight (8 outstanding VMEM)
    VQ_GLL(0, 0);
    VQ_GLL(1, 32);
    #pragma unroll
    for (int t = 0; t < 16; ++t) {
        if (t + 2 < 16) VQ_GLL((t + 2) & 3, (t + 2) * 32);   // 4 more -> 12 outstanding
        // wait until batch t's 4 ops retired (in-order retirement, m135)
        if (t <= 13)      asm volatile("s_waitcnt vmcnt(8)" ::: "memory");
        else if (t == 14) asm volatile("s_waitcnt vmcnt(4)" ::: "memory");
        else              asm volatile("s_waitcnt vmcnt(0)" ::: "memory");
        __builtin_amdgcn_s_barrier();                         // everyone's batch t landed
        __builtin_amdgcn_sched_barrier(0);                    // pin ds_reads below barrier
        VQ_COMPUTE(t & 3);
    }
#undef VQ_GLL
#undef VQ_COMPUTE

    float c2v[8];
    #pragma unroll
    for (int nt = 0; nt < 8; ++nt) c2v[nt] = c2[n0 + wn * 128 + nt * 16 + lm];

    u64* scr = (u64*)&As[0][0];   // [2 wn][256 tokens][2] = 1024 u64 = 8KB (fits in As[0])
    #pragma unroll
    for (int mt = 0; mt < 4; ++mt) {
        #pragma unroll
        for (int rg = 0; rg < 4; ++rg) {
            int tl = wm * 64 + mt * 16 + quad * 4 + rg;
            u64 k1 = ~0ull, k2 = ~0ull;
            #pragma unroll
            for (int nt = 0; nt < 8; ++nt) {
                float d = c2v[nt] - 2.0f * acc[mt][nt][rg];
                u64 k = packkey(d, n0 + wn * 128 + nt * 16 + lm);
                if (k < k1) { k2 = k1; k1 = k; } else if (k < k2) { k2 = k; }
            }
            #pragma unroll
            for (int s = 1; s < 16; s <<= 1) {
                u64 o1 = shfl_xor_u64_w16(k1, s);
                u64 o2 = shfl_xor_u64_w16(k2, s);
                merge2(k1, k2, o1, o2);
            }
            if (lm == 0) { scr[wn * 512 + tl * 2] = k1; scr[wn * 512 + tl * 2 + 1] = k2; }
        }
    }
    __syncthreads();
    if (tid < 256) {
        u64 a1 = scr[tid * 2], a2 = scr[tid * 2 + 1];
        merge2(a1, a2, scr[512 + tid * 2], scr[512 + tid * 2 + 1]);
        size_t base = (size_t)(m0 + tid) * 8 + nblk * 2;
        pairs[base] = a1; pairs[base + 1] = a2;
    }
}

// ---------------- fused reduce + q1 residual prep (q0 path) ----------------
__global__ void vq_reduce_prep(const u64* __restrict__ pairs, u64* __restrict__ keybuf,
                               int* __restrict__ fc, int* __restrict__ flaglist, float tau,
                               const u16* __restrict__ xrh, const u16* __restrict__ cbh0,
                               u16* __restrict__ r1h) {
    int tid = threadIdx.x;
    int g = tid >> 5, l = tid & 31;
    int m = blockIdx.x * 8 + g;
    u64 k1 = ~0ull, k2 = ~0ull;
    if (l < 8) k1 = pairs[(size_t)m * 8 + l];
    #pragma unroll
    for (int s = 1; s < 8; s <<= 1) {
        u64 o1 = shfl_xor_u64_w16(k1, s);
        u64 o2 = shfl_xor_u64_w16(k2, s);
        merge2(k1, k2, o1, o2);
    }
    int i0 = (int)(k1 & 0xFFFFFFFFull);
    i0 = __shfl(i0, 0, 32);            // broadcast from lane 0 of each 32-group
    if (l == 0) {
        keybuf[m] = k1;
        if (unpackd(k2) - unpackd(k1) < tau) {
            int pos = atomicAdd(fc, 1);
            flaglist[pos] = m;
        }
    }
    const half8* xp = (const half8*)(xrh + (size_t)m * 512 + l * 16);
    const half8* cp = (const half8*)(cbh0 + (size_t)i0 * 512 + l * 16);
    half8* rp = (half8*)(r1h + (size_t)m * 512 + l * 16);
    rp[0] = xp[0] - cp[0];
    rp[1] = xp[1] - cp[1];
}

// ---------------- reduce: global top2 per token from 4 block-pairs (q1 path) ----------------
__global__ void vq_reduce(const u64* __restrict__ pairs, u64* __restrict__ keybuf,
                          int* __restrict__ fc, int* __restrict__ flaglist, float tau) {
    int m = blockIdx.x * 256 + threadIdx.x;
    const u64* p = pairs + (size_t)m * 8;
    u64 k1 = ~0ull, k2 = ~0ull;
    #pragma unroll
    for (int i = 0; i < 8; ++i) {
        u64 k = p[i];
        if (k < k1) { k2 = k1; k1 = k; } else if (k < k2) { k2 = k; }
    }
    keybuf[m] = k1;
    if (unpackd(k2) - unpackd(k1) < tau) {
        int pos = atomicAdd(fc, 1);
        flaglist[pos] = m;
    }
}

// ---------------- rescue: exact fp32 argmin for flagged tokens ----
__global__ void vq_rescue(const float* __restrict__ xr, const float* __restrict__ cb,
                          const float* __restrict__ c2, const float* __restrict__ cb0,
                          const u64* __restrict__ prevkeys,
                          const int* __restrict__ fc, const int* __restrict__ flaglist,
                          u64* __restrict__ keybuf) {
    __shared__ u64 red[4];
    int cnt = *fc;
    int lane = threadIdx.x & 63, wid = threadIdx.x >> 6;
    for (int f = blockIdx.x; f < cnt; f += gridDim.x) {
        int m = flaglist[f];
        float4 rv0 = *(const float4*)(xr + (size_t)m * 512 + lane * 8);
        float4 rv1 = *(const float4*)(xr + (size_t)m * 512 + lane * 8 + 4);
        if (cb0) {
            size_t co = (size_t)(prevkeys[m] & 0xFFFFFFFFull) * 512;
            float4 c0 = *(const float4*)(cb0 + co + lane * 8);
            float4 c1 = *(const float4*)(cb0 + co + lane * 8 + 4);
            rv0.x -= c0.x; rv0.y -= c0.y; rv0.z -= c0.z; rv0.w -= c0.w;
            rv1.x -= c1.x; rv1.y -= c1.y; rv1.z -= c1.z; rv1.w -= c1.w;
        }
        u64 best = ~0ull;
        for (int c = wid * 256; c < wid * 256 + 256; ++c) {
            const float* cp = cb + (size_t)c * 512 + lane * 8;
            float4 c0 = *(const float4*)cp;
            float4 c1 = *(const float4*)(cp + 4);
            float p = rv0.x*c0.x + rv0.y*c0.y + rv0.z*c0.z + rv0.w*c0.w
                    + rv1.x*c1.x + rv1.y*c1.y + rv1.z*c1.z + rv1.w*c1.w;
            #pragma unroll
            for (int s = 1; s < 64; s <<= 1) p += __shfl_xor(p, s, 64);
            u64 k = packkey(c2[c] - 2.0f * p, c);
            if (k < best) best = k;
        }
        if (lane == 0) red[wid] = best;
        __syncthreads();
        if (threadIdx.x == 0) {
            u64 b = red[0];
            if (red[1] < b) b = red[1];
            if (red[2] < b) b = red[2];
            if (red[3] < b) b = red[3];
            keybuf[m] = b;
        }
        __syncthreads();
    }
}

// ---------------- commit + indices + decoder-stage1 gather (wave per token) ----------------
// d1 values computed with the IDENTICAL expression as the old d1_gather kernel -> bit-exact.
__global__ void commit_idx_kernel(const float* __restrict__ xr,
                                  const float* __restrict__ cb0f, const float* __restrict__ cb1f,
                                  const u64* __restrict__ keys0, const u64* __restrict__ keys1,
                                  float* __restrict__ idx_f, int* __restrict__ idx_i,
                                  float* __restrict__ slots,
                                  const float* __restrict__ P0, const float* __restrict__ P1,
                                  const float* __restrict__ bx1, float* __restrict__ d1) {
    int tid = threadIdx.x;
    int lane = tid & 63;
    int m = blockIdx.x * 4 + (tid >> 6);
    unsigned i0 = (unsigned)(keys0[m] & 0xFFFFFFFFull);
    unsigned i1 = (unsigned)(keys1[m] & 0xFFFFFFFFull);
    const float* x = xr + (size_t)m * 512 + lane * 8;
    const float* c0 = cb0f + (size_t)i0 * 512 + lane * 8;
    const float* c1 = cb1f + (size_t)i1 * 512 + lane * 8;
    float4 x0 = *(const float4*)x, x1 = *(const float4*)(x + 4);
    float4 a0 = *(const float4*)c0, a1 = *(const float4*)(c0 + 4);
    float4 b0 = *(const float4*)c1, b1 = *(const float4*)(c1 + 4);
    x0.x -= a0.x; x0.y -= a0.y; x0.z -= a0.z; x0.w -= a0.w;
    x1.x -= a1.x; x1.y -= a1.y; x1.z -= a1.z; x1.w -= a1.w;
    float s1 = x0.x*x0.x + x0.y*x0.y + x0.z*x0.z + x0.w*x0.w
             + x1.x*x1.x + x1.y*x1.y + x1.z*x1.z + x1.w*x1.w;
    x0.x -= b0.x; x0.y -= b0.y; x0.z -= b0.z; x0.w -= b0.w;
    x1.x -= b1.x; x1.y -= b1.y; x1.z -= b1.z; x1.w -= b1.w;
    float s2 = x0.x*x0.x + x0.y*x0.y + x0.z*x0.z + x0.w*x0.w
             + x1.x*x1.x + x1.y*x1.y + x1.z*x1.z + x1.w*x1.w;
    #pragma unroll
    for (int o = 32; o > 0; o >>= 1) { s1 += __shfl_down(s1, o, 64); s2 += __shfl_down(s2, o, 64); }
    if (lane == 0) {
        atomicAdd(&slots[512 + (m & 511)], s1);
        atomicAdd(&slots[1024 + (m & 511)], s2);
        idx_f[(size_t)m * 2]     = (float)i0;
        idx_f[(size_t)m * 2 + 1] = (float)i1;
        idx_i[m * 2] = (int)i0;
        idx_i[m * 2 + 1] = (int)i1;
    }
    // decoder stage-1 gather: 128 values per token, 2 per lane (same expression as d1_gather)
    {
        int b = m / T4L, t4 = m % T4L;
        int n = lane;
        float v = P0[(int)i0 * 128 + n] + P1[(int)i1 * 128 + n] + bx1[n];
        v = fmaxf(v, 0.f);
        d1[((size_t)(b * T2L + 2 * t4 + (n & 1))) * 64 + (n >> 1)] = v;
        int n2 = lane + 64;
        float v2 = P0[(int)i0 * 128 + n2] + P1[(int)i1 * 128 + n2] + bx1[n2];
        v2 = fmaxf(v2, 0.f);
        d1[((size_t)(b * T2L + 2 * t4 + (n2 & 1))) * 64 + (n2 >> 1)] = v2;
    }
}

// ---------------- quantized output (channel-major) via LDS transpose ----------------
__global__ void quant_out_kernel(const float* __restrict__ cb0, const float* __restrict__ cb1,
                                 const int* __restrict__ idxi, float* __restrict__ out4) {
    __shared__ float buf[64][129];
    __shared__ int i0s[64], i1s[64];
    int b = blockIdx.x;
    int t0 = blockIdx.y * 64;
    int c0 = blockIdx.z * 128;
    int tid = threadIdx.x;
    if (tid < 64) {
        int t = t0 + tid;
        int i0 = 0, i1 = 0;
        if (t < T4L) { i0 = idxi[(b * T4L + t) * 2]; i1 = idxi[(b * T4L + t) * 2 + 1]; }
        i0s[tid] = i0; i1s[tid] = i1;
    }
    __syncthreads();
    int cl = tid & 127, th = tid >> 7;
    for (int t = th; t < 64; t += 2) {
        if (t0 + t < T4L)
            buf[t][cl] = cb0[(size_t)i0s[t] * 512 + c0 + cl] + cb1[(size_t)i1s[t] * 512 + c0 + cl];
    }
    __syncthreads();
    int lane = tid & 63, ch = tid >> 6;
    for (int cc = ch; cc < 128; cc += 4) {
        int t = t0 + lane;
        if (t < T4L) out4[((size_t)b * 512 + c0 + cc) * T4L + t] = buf[lane][cc];
    }
}

// ---------------- fused convT2 + final 1x1 conv + recon loss ----------------
__global__ __launch_bounds__(256) void dec2_fused(
    const float* __restrict__ d1, const float* __restrict__ Bd2, const float* __restrict__ bx2,
    const float* __restrict__ W3, const float* __restrict__ b3, const float* __restrict__ img,
    float* __restrict__ out, float* __restrict__ slots)
{
    __shared__ float As[32][132];
    __shared__ float Bs[32][132];
    __shared__ float w3s[64];
    int m0 = blockIdx.x * 128;
    int tid = threadIdx.x;
    int tx = tid & 15;
    int ty = tid >> 4;
    if (tid < 64) w3s[tid] = W3[tid];
    float acc[8][8];
    #pragma unroll
    for (int i = 0; i < 8; ++i)
        #pragma unroll
        for (int j = 0; j < 8; ++j) acc[i][j] = 0.f;

    for (int k0 = 0; k0 < 64; k0 += 32) {
        #pragma unroll
        for (int i = 0; i < 4; ++i) {
            int idx = tid + i * 256;
            int row = idx >> 3;
            int kq = idx & 7;
            float4 v = *(const float4*)(d1 + (size_t)(m0 + row) * 64 + k0 + kq * 4);
            int kk = kq * 4;
            As[kk + 0][row] = v.x; As[kk + 1][row] = v.y;
            As[kk + 2][row] = v.z; As[kk + 3][row] = v.w;
        }
        #pragma unroll
        for (int i = 0; i < 4; ++i) {
            int idx = tid + i * 256;
            int row = idx >> 3;
            int kq = idx & 7;
            float4 v = *(const float4*)(Bd2 + (size_t)row * 64 + k0 + kq * 4);
            int kk = kq * 4;
            Bs[kk + 0][row] = v.x; Bs[kk + 1][row] = v.y;
            Bs[kk + 2][row] = v.z; Bs[kk + 3][row] = v.w;
        }
        __syncthreads();
        #pragma unroll
        for (int kk = 0; kk < 32; ++kk) {
            float a[8], bf[8];
            float4 a0 = *(const float4*)&As[kk][ty * 8];
            float4 a1 = *(const float4*)&As[kk][ty * 8 + 4];
            a[0]=a0.x; a[1]=a0.y; a[2]=a0.z; a[3]=a0.w;
            a[4]=a1.x; a[5]=a1.y; a[6]=a1.z; a[7]=a1.w;
            float4 b0 = *(const float4*)&Bs[kk][tx * 4];
            float4 b1 = *(const float4*)&Bs[kk][64 + tx * 4];
            bf[0]=b0.x; bf[1]=b0.y; bf[2]=b0.z; bf[3]=b0.w;
            bf[4]=b1.x; bf[5]=b1.y; bf[6]=b1.z; bf[7]=b1.w;
            #pragma unroll
            for (int i = 0; i < 8; ++i)
                #pragma unroll
                for (int j = 0; j < 8; ++j) acc[i][j] += a[i] * bf[j];
        }
        __syncthreads();
    }
    float bb3 = b3[0];
    float local = 0.f;
    #pragma unroll
    for (int i = 0; i < 8; ++i) {
        float s0 = 0.f, s1 = 0.f;
        #pragma unroll
        for (int j = 0; j < 4; ++j) {
            int n = tx * 4 + j;
            float v = fmaxf(acc[i][j] + bx2[n], 0.f);
            float w = w3s[n >> 1];
            if (j & 1) s1 += w * v; else s0 += w * v;
            int n2 = 64 + tx * 4 + j;
            float v2 = fmaxf(acc[i][j + 4] + bx2[n2], 0.f);
            float w2 = w3s[n2 >> 1];
            if (j & 1) s1 += w2 * v2; else s0 += w2 * v2;
        }
        #pragma unroll
        for (int o = 8; o > 0; o >>= 1) { s0 += __shfl_down(s0, o, 16); s1 += __shfl_down(s1, o, 16); }
        if (tx == 0) {
            int m = m0 + ty * 8 + i;
            int b = m / T2L, t2 = m % T2L;
            size_t o0 = (size_t)b * TLEN + 2 * t2;
            float v0 = s0 + bb3, v1 = s1 + bb3;
            out[o0] = v0; out[o0 + 1] = v1;
            float e0 = img[o0] - v0, e1 = img[o0 + 1] - v1;
            local += e0 * e0 + e1 * e1;
        }
    }
    if (tx == 0) atomicAdd(&slots[(blockIdx.x * 16 + ty) & 511], local);
}

// ---------------- finalize losses ----------------
__global__ void finalize_kernel(const float* __restrict__ slots, float* __restrict__ out_scalars) {
    __shared__ float red[256];
    int tid = threadIdx.x;
    for (int which = 0; which < 3; ++which) {
        float s = slots[which * 512 + tid] + slots[which * 512 + tid + 256];
        red[tid] = s; __syncthreads();
        for (int st = 128; st > 0; st >>= 1) { if (tid < st) red[tid] += red[tid + st]; __syncthreads(); }
        if (tid == 0) {
            float denom = (which == 0) ? (float)MOUT : (float)((size_t)MTOK * 512);
            out_scalars[which] = red[0] / denom;
        }
        __syncthreads();
    }
}

// ---------------- launch ----------------
extern "C" void kernel_launch(void* const* d_in, const int* in_sizes, int n_in,
                              void* d_out, int out_size, void* d_ws, size_t ws_size,
                              hipStream_t stream) {
    const float* img  = (const float*)d_in[0];
    const float* We1  = (const float*)d_in[1];
    const float* be1  = (const float*)d_in[2];
    const float* We2  = (const float*)d_in[3];
    const float* be2  = (const float*)d_in[4];
    const float* We3  = (const float*)d_in[5];
    const float* be3  = (const float*)d_in[6];
    const float* cbs  = (const float*)d_in[7];
    const float* Wtd1 = (const float*)d_in[8];
    const float* bd1  = (const float*)d_in[9];
    const float* Wtd2 = (const float*)d_in[10];
    const float* bd2  = (const float*)d_in[11];
    const float* Wd3  = (const float*)d_in[12];
    const float* bd3  = (const float*)d_in[13];

    float* w = (float*)d_ws;
    float* xr   = w + OFF_XR;
    float* h1   = w + OFF_H1;
    float* h2   = w + OFF_H2;
    float* Be2  = w + OFF_BE2;
    float* Bd1  = w + OFF_BD1;
    float* Bd2  = w + OFF_BD2;
    float* bx1  = w + OFF_BX1;
    float* bx2  = w + OFF_BX2;
    float* zerob= w + OFF_ZB;
    float* c2   = w + OFF_C2;
    float* slots= w + OFF_SLOT;
    int*   idxi = (int*)(w + OFF_IDXI);
    u64*   keys = (u64*)(w + OFF_KEYS);
    int*   fc   = (int*)(w + OFF_FC);
    int*   flag = (int*)(w + OFF_FLAG);
    u16*   cbh  = (u16*)(w + OFF_CBH);
    float* P0   = w + OFF_P0;
    float* P1   = w + OFF_P1;
    u64*   pairs= (u64*)(w + OFF_PAIRS);

    float* outp = (float*)d_out;
    float* out0   = outp + DO_OUT;
    float* oscal  = outp + DO_RECON;
    float* idxf   = outp + DO_IDX;
    float* qout   = outp + DO_QUANT;
    // d_out scratch (dead until commit/quant_out, which run after all consumers):
    u16*   xrh    = (u16*)(outp + DO_XRH);
    u16*   r1h    = (u16*)(outp + DO_R1H);

    hipMemsetAsync(slots, 0, 1536 * sizeof(float), stream);
    hipMemsetAsync(fc, 0, 2 * sizeof(int), stream);
    hipMemsetAsync(zerob, 0, 128 * sizeof(float), stream);

    setup_kernel<<<1024, 256, 0, stream>>>(We2, Wtd1, Wtd2, bd1, bd2, cbs,
                                           Be2, Bd1, Bd2, bx1, bx2, cbh, c2);

    const float* cb1p = cbs + (size_t)NTOK * CBD;

    // decoder stage-1 code tables: P = cb . Bd1^T  (P0,P1 contiguous -> single M=2048 gemm)
    gemm_nt<<<dim3(16, 2), 256, 0, stream>>>(cbs, Bd1, zerob, P0, 2048, 128, 512, 0, 0, nullptr);

    // encoder
    enc1_kernel<<<(NB * T2L * HIDC) / 256, 256, 0, stream>>>(img, We1, be1, h1);
    gemm_nt<<<dim3(MTOK / 128, 1), 256, 0, stream>>>(h1, Be2, be2, h2, MTOK, 64, 128, 1, 1, nullptr);
    gemm_nt<<<dim3(MTOK / 128, 8), 256, 0, stream>>>(h2, We3, be3, xr, MTOK, 512, 64, 0, 0, xrh);

    // residual VQ, q = 0: pipelined pure-gll fp16 MFMA, TAU 0.05
    vq_f16_gll<<<dim3(4, MTOK / 256), 512, 0, stream>>>(xrh, cbh, c2, pairs);
    // fused reduce + r1h prep (bit-identical to vq_reduce + r1_prep)
    vq_reduce_prep<<<MTOK / 8, 256, 0, stream>>>(pairs, keys, fc + 0, flag, 0.05f, xrh, cbh, r1h);
    vq_rescue<<<1024, 256, 0, stream>>>(xr, cbs, c2, nullptr, nullptr, fc + 0, flag, keys);
    // q = 1: TAU 0.15
    vq_f16_gll<<<dim3(4, MTOK / 256), 512, 0, stream>>>(r1h, cbh + (size_t)NTOK * 512, c2 + NTOK, pairs);
    vq_reduce<<<MTOK / 256, 256, 0, stream>>>(pairs, keys + MTOK, fc + 1, flag + MTOK, 0.15f);
    vq_rescue<<<1024, 256, 0, stream>>>(xr, cb1p, c2 + NTOK, cbs, keys, fc + 1, flag + MTOK, keys + MTOK);

    // indices + exact commit losses + decoder-stage1 gather (d1 written into h1 buffer)
    commit_idx_kernel<<<MTOK / 4, 256, 0, stream>>>(xr, cbs, cb1p, keys, keys + MTOK, idxf, idxi,
                                                    slots, P0, P1, bx1, h1);

    // quantized output [B,512,408] (overwrites dead r1h region -- safe)
    quant_out_kernel<<<dim3(NB, 7, 4), 256, 0, stream>>>(cbs, cb1p, idxi, qout);

    // decoder: fused convT2+final+recon (reads d1 from h1 buffer)
    dec2_fused<<<M2TOK / 128, 256, 0, stream>>>(h1, Bd2, bx2, Wd3, bd3, img, out0, slots);

    finalize_kernel<<<1, 256, 0, stream>>>(slots, oscal);
}